// Round 7
// baseline (4312.962 us; speedup 1.0000x reference)
//
#include <hip/hip_runtime.h>
#include <math.h>

#define M_SLOTS 8192
#define N_DIM   4096
#define FVS     64
#define PLEN    64
#define CDIM    256
#define NIN     512
#define NOUT    512
#define STEPS   8
#define EPS_F   1e-8f

#define RCHUNK  16
#define NCHUNKS (M_SLOTS / RCHUNK)      // 512

// ---------------- helpers ----------------

__device__ inline float wave_sum(float v) {
    for (int off = 32; off; off >>= 1) v += __shfl_down(v, off);
    return v;
}

// 256-thread block sum; sh >= 4 floats; all threads get result
__device__ inline float blk_sum_256(float v, float* sh) {
    v = wave_sum(v);
    int lane = threadIdx.x & 63, wid = threadIdx.x >> 6;
    if (lane == 0) sh[wid] = v;
    __syncthreads();
    float r = sh[0] + sh[1] + sh[2] + sh[3];
    __syncthreads();
    return r;
}

// ---------------- kernels ----------------

// X = x @ input_embedding, then c = sigmoid(Wc @ concat(X, prog0) + bc); zero counters
__global__ void k_init_ctrl(const float* __restrict__ x, const float* __restrict__ emb,
                            const float* __restrict__ prog0,
                            const float* __restrict__ Wc, const float* __restrict__ bc,
                            float* __restrict__ X, float* __restrict__ c,
                            unsigned int* __restrict__ cnt) {
    __shared__ float in[FVS + PLEN];
    int tid = threadIdx.x;  // 256
    if (tid < STEPS) cnt[tid] = 0u;
    if (tid < FVS) {
        float acc = 0.f;
        for (int i = 0; i < NIN; ++i) acc += x[i] * emb[i * FVS + tid];
        X[tid] = acc;
        in[tid] = acc;
    } else if (tid < FVS + PLEN) {
        in[tid] = prog0[tid - FVS];
    }
    __syncthreads();
    float acc = bc[tid];
    const float* wrow = Wc + tid * (FVS + PLEN);
    #pragma unroll 8
    for (int i = 0; i < FVS + PLEN; ++i) acc += wrow[i] * in[i];
    c[tid] = 1.f / (1.f + expf(-acc));
}

// one wave -> key rows (all four outputs), cv = controller as float4 per lane
__device__ inline void keys_row(int gw, float4 cv, int lane, const float* __restrict__ prog,
                                const float* __restrict__ Wk, const float* __restrict__ bk,
                                const float* __restrict__ We, const float* __restrict__ be,
                                const float* __restrict__ Wa, const float* __restrict__ ba,
                                const float* __restrict__ Wrk, const float* __restrict__ brk,
                                float* __restrict__ k, float* __restrict__ e,
                                float* __restrict__ a, float* __restrict__ kr) {
    float4 wv;
    wv = ((const float4*)(Wk + (size_t)gw * CDIM))[lane];
    float sK = wv.x*cv.x + wv.y*cv.y + wv.z*cv.z + wv.w*cv.w;
    wv = ((const float4*)(We + (size_t)gw * CDIM))[lane];
    float sE = wv.x*cv.x + wv.y*cv.y + wv.z*cv.z + wv.w*cv.w;
    wv = ((const float4*)(Wa + (size_t)gw * CDIM))[lane];
    float sA = wv.x*cv.x + wv.y*cv.y + wv.z*cv.z + wv.w*cv.w;
    float sR = Wrk[(size_t)gw * PLEN + lane] * prog[lane];
    sK = wave_sum(sK); sE = wave_sum(sE); sA = wave_sum(sA); sR = wave_sum(sR);
    if (lane == 0) {
        k[gw]  = tanhf(sK + bk[gw]);
        e[gw]  = 1.f / (1.f + expf(-(sE + be[gw])));
        a[gw]  = tanhf(sA + ba[gw]);
        kr[gw] = tanhf(sR + brk[gw]);
    }
}

// standalone keys (step 0): reads global c.  grid 512 x 256
__global__ __launch_bounds__(256) void k_keys4(
        const float* __restrict__ c, const float* __restrict__ prog,
        const float* __restrict__ Wk, const float* __restrict__ bk,
        const float* __restrict__ We, const float* __restrict__ be,
        const float* __restrict__ Wa, const float* __restrict__ ba,
        const float* __restrict__ Wrk, const float* __restrict__ brk,
        float* __restrict__ k, float* __restrict__ e,
        float* __restrict__ a, float* __restrict__ kr) {
    int lane = threadIdx.x & 63, wid = threadIdx.x >> 6;
    const float4 cv = ((const float4*)c)[lane];
    for (int gw = blockIdx.x * 4 + wid; gw < 4096; gw += 2048)
        keys_row(gw, cv, lane, prog, Wk, bk, We, be, Wa, ba, Wrk, brk, k, e, a, kr);
}

// 8 row-reductions over mem (2 rows/block, grid 4096 x 256), then the LAST block
// to finish runs the dual-softmax addressing (write ww + analytic read wr).
// stat rows: 0 mem.k  1 mem.kr  2 mem.(e*kr)  3 mem.a  4 mem.(e*a)
//            5 |mem|^2  6 mem^2.e  7 mem^2.e^2
__global__ __launch_bounds__(256) void k_sim8_addr(
        const float* __restrict__ mem,
        const float* __restrict__ k, const float* __restrict__ kr,
        const float* __restrict__ a, const float* __restrict__ e,
        float* __restrict__ stat, float* __restrict__ ww, float* __restrict__ wr,
        unsigned int* __restrict__ cnt) {
    const int m0 = blockIdx.x, m1 = blockIdx.x + 4096;
    const int tid = threadIdx.x;
    const float4* r0 = (const float4*)(mem + (size_t)m0 * N_DIM);
    const float4* r1 = (const float4*)(mem + (size_t)m1 * N_DIM);
    const float4* K4 = (const float4*)k;
    const float4* R4 = (const float4*)kr;
    const float4* A4 = (const float4*)a;
    const float4* E4 = (const float4*)e;
    float s0=0,s1=0,s2=0,s3=0,s4=0,s5=0,s6=0,s7=0;
    float u0=0,u1=0,u2=0,u3=0,u4=0,u5=0,u6=0,u7=0;
    #pragma unroll
    for (int ii = 0; ii < 4; ++ii) {
        int i = tid + ii * 256;
        float4 kk = K4[i];
        float4 rr = R4[i];
        float4 aa = A4[i];
        float4 ee = E4[i];
        float4 v0 = r0[i];
        float4 v1 = r1[i];
        #define ACC1(S0,S1,S2,S3,S4,S5,S6,S7,vv,kc,rc,ac,ec) { \
            float _v=vv,_k=kc,_r=rc,_a=ac,_e=ec; \
            float _ve=_v*_e, _v2=_v*_v, _v2e=_v2*_e; \
            S0+=_v*_k; S1+=_v*_r; S2+=_ve*_r; S3+=_v*_a; S4+=_ve*_a; \
            S5+=_v2; S6+=_v2e; S7+=_v2e*_e; }
        ACC1(s0,s1,s2,s3,s4,s5,s6,s7, v0.x, kk.x, rr.x, aa.x, ee.x)
        ACC1(s0,s1,s2,s3,s4,s5,s6,s7, v0.y, kk.y, rr.y, aa.y, ee.y)
        ACC1(s0,s1,s2,s3,s4,s5,s6,s7, v0.z, kk.z, rr.z, aa.z, ee.z)
        ACC1(s0,s1,s2,s3,s4,s5,s6,s7, v0.w, kk.w, rr.w, aa.w, ee.w)
        ACC1(u0,u1,u2,u3,u4,u5,u6,u7, v1.x, kk.x, rr.x, aa.x, ee.x)
        ACC1(u0,u1,u2,u3,u4,u5,u6,u7, v1.y, kk.y, rr.y, aa.y, ee.y)
        ACC1(u0,u1,u2,u3,u4,u5,u6,u7, v1.z, kk.z, rr.z, aa.z, ee.z)
        ACC1(u0,u1,u2,u3,u4,u5,u6,u7, v1.w, kk.w, rr.w, aa.w, ee.w)
        #undef ACC1
    }
    s0=wave_sum(s0); s1=wave_sum(s1); s2=wave_sum(s2); s3=wave_sum(s3);
    s4=wave_sum(s4); s5=wave_sum(s5); s6=wave_sum(s6); s7=wave_sum(s7);
    u0=wave_sum(u0); u1=wave_sum(u1); u2=wave_sum(u2); u3=wave_sum(u3);
    u4=wave_sum(u4); u5=wave_sum(u5); u6=wave_sum(u6); u7=wave_sum(u7);
    __shared__ float shc[4][16];
    int lane = tid & 63, wid = tid >> 6;
    if (lane == 0) {
        shc[wid][0]=s0; shc[wid][1]=s1; shc[wid][2]=s2; shc[wid][3]=s3;
        shc[wid][4]=s4; shc[wid][5]=s5; shc[wid][6]=s6; shc[wid][7]=s7;
        shc[wid][8]=u0; shc[wid][9]=u1; shc[wid][10]=u2; shc[wid][11]=u3;
        shc[wid][12]=u4; shc[wid][13]=u5; shc[wid][14]=u6; shc[wid][15]=u7;
    }
    __syncthreads();
    if (tid < 16) {
        float tot = shc[0][tid] + shc[1][tid] + shc[2][tid] + shc[3][tid];
        int m = (tid < 8) ? m0 : m1;
        stat[(size_t)(tid & 7) * M_SLOTS + m] = tot;
    }

    // ---- completion detect: last block runs addressing ----
    __syncthreads();
    __threadfence();
    __shared__ int lastf;
    if (tid == 0) lastf = (atomicAdd(cnt, 1u) == (unsigned int)(gridDim.x - 1)) ? 1 : 0;
    __syncthreads();
    if (!lastf) return;
    __threadfence();   // acquire: all blocks' stat stores visible

    __shared__ float sh4[4];
    // dots: d0=k.k d1=kr.kr d2=a.kr d3=a.a
    float a0=0, a1=0, a2=0, a3=0;
    for (int i = tid; i < N_DIM; i += 256) {
        float kv = k[i], rv = kr[i], av = a[i];
        a0 += kv*kv; a1 += rv*rv; a2 += av*rv; a3 += av*av;
    }
    float d0 = blk_sum_256(a0, sh4);
    float d1 = blk_sum_256(a1, sh4);
    float d2 = blk_sum_256(a2, sh4);
    float d3 = blk_sum_256(a3, sh4);
    float knorm = sqrtf(d0), krnorm = sqrtf(d1);

    const float* simk = stat + 0 * (size_t)M_SLOTS;
    const float* skr  = stat + 1 * (size_t)M_SLOTS;
    const float* sekr = stat + 2 * (size_t)M_SLOTS;
    const float* sa   = stat + 3 * (size_t)M_SLOTS;
    const float* sea  = stat + 4 * (size_t)M_SLOTS;
    const float* n2o  = stat + 5 * (size_t)M_SLOTS;
    const float* qe   = stat + 6 * (size_t)M_SLOTS;
    const float* qe2  = stat + 7 * (size_t)M_SLOTS;

    // write softmax (no max-subtract: cosine in [-1,1]) ; ww holds exp temporarily
    float ls = 0.f;
    for (int m = tid; m < M_SLOTS; m += 256) {
        float v = simk[m] / (sqrtf(n2o[m]) * knorm + EPS_F);
        float ex = expf(v);
        ww[m] = ex;
        ls += ex;
    }
    ls = blk_sum_256(ls, sh4);
    float inv = 1.f / ls;

    // read softmax from analytic sim/norm of the UPDATED memory
    float ls2 = 0.f;
    for (int m = tid; m < M_SLOTS; m += 256) {
        float w1 = ww[m] * inv;
        ww[m] = w1;
        float sim2 = skr[m] - w1 * sekr[m] + w1 * d2;
        float n2n  = n2o[m] - 2.f*w1*qe[m] + w1*w1*qe2[m]
                   + 2.f*w1*sa[m] - 2.f*w1*w1*sea[m] + w1*w1*d3;
        float v = sim2 / (sqrtf(n2n) * krnorm + EPS_F);
        float ex = expf(v);
        wr[m] = ex;
        ls2 += ex;
    }
    ls2 = blk_sum_256(ls2, sh4);
    float inv2 = 1.f / ls2;
    for (int m = tid; m < M_SLOTS; m += 256) wr[m] *= inv2;
}

// mem_new = mem_old*(1-ww*e) + ww*a ; partial[rc] = sum wr*mem_new over 16 rows.
// grid (4, 512) x 256.  May run IN PLACE (src==dst); each element touched by one thread.
__global__ void k_update_read(const float* src, float* dst,
                              const float* __restrict__ ww, const float* __restrict__ wr,
                              const float* __restrict__ e, const float* __restrict__ a,
                              float* __restrict__ partial, int write_mem) {
    int c4 = blockIdx.x * 256 + threadIdx.x;   // [0, 1024)
    int rc = blockIdx.y;                       // [0, 512)
    int r0 = rc * RCHUNK;
    const float4* s4 = (const float4*)src;
    float4*       d4 = (float4*)dst;
    float4 ee = ((const float4*)e)[c4];
    float4 aa = ((const float4*)a)[c4];
    float4 acc = make_float4(0.f, 0.f, 0.f, 0.f);
    if (write_mem) {
        #pragma unroll
        for (int r = r0; r < r0 + RCHUNK; ++r) {
            float w1 = ww[r], w2 = wr[r];
            float4 v = s4[(size_t)r * (N_DIM / 4) + c4];
            float4 nv;
            nv.x = v.x * (1.f - w1 * ee.x) + w1 * aa.x;
            nv.y = v.y * (1.f - w1 * ee.y) + w1 * aa.y;
            nv.z = v.z * (1.f - w1 * ee.z) + w1 * aa.z;
            nv.w = v.w * (1.f - w1 * ee.w) + w1 * aa.w;
            d4[(size_t)r * (N_DIM / 4) + c4] = nv;
            acc.x += w2 * nv.x; acc.y += w2 * nv.y; acc.z += w2 * nv.z; acc.w += w2 * nv.w;
        }
    } else {
        #pragma unroll
        for (int r = r0; r < r0 + RCHUNK; ++r) {
            float w1 = ww[r], w2 = wr[r];
            float4 v = s4[(size_t)r * (N_DIM / 4) + c4];
            float4 nv;
            nv.x = v.x * (1.f - w1 * ee.x) + w1 * aa.x;
            nv.y = v.y * (1.f - w1 * ee.y) + w1 * aa.y;
            nv.z = v.z * (1.f - w1 * ee.z) + w1 * aa.z;
            nv.w = v.w * (1.f - w1 * ee.w) + w1 * aa.w;
            acc.x += w2 * nv.x; acc.y += w2 * nv.y; acc.z += w2 * nv.z; acc.w += w2 * nv.w;
        }
    }
    ((float4*)partial)[(size_t)rc * (N_DIM / 4) + c4] = acc;
}

// red[c] = sum over 512 partial rows.  grid 64 x 256.
__global__ void k_read_reduce(const float* __restrict__ partial, float* __restrict__ red) {
    __shared__ float gsh[4][64];
    int l = threadIdx.x & 63;
    int q = threadIdx.x >> 6;
    int c = blockIdx.x * 64 + l;
    float acc = 0.f;
    #pragma unroll 8
    for (int r = q * 128; r < q * 128 + 128; ++r)
        acc += partial[(size_t)r * N_DIM + c];
    gsh[q][l] = acc;
    __syncthreads();
    if (threadIdx.x < 64)
        red[blockIdx.x * 64 + threadIdx.x] =
            gsh[0][threadIdx.x] + gsh[1][threadIdx.x] + gsh[2][threadIdx.x] + gsh[3][threadIdx.x];
}

// X_new = tanh(X_old @ red); c = sigmoid(Wc [X_new, prog_next] + bc); then next keys.
// grid 512 x 256.  Only block 0 writes X_new.
__global__ __launch_bounds__(256) void k_exec_keys(
        const float* __restrict__ Xold, float* __restrict__ Xnew,
        const float* __restrict__ red, const float* __restrict__ prog_next,
        const float* __restrict__ Wc, const float* __restrict__ bc,
        const float* __restrict__ Wk, const float* __restrict__ bk,
        const float* __restrict__ We, const float* __restrict__ be,
        const float* __restrict__ Wa, const float* __restrict__ ba,
        const float* __restrict__ Wrk, const float* __restrict__ brk,
        float* __restrict__ k, float* __restrict__ e,
        float* __restrict__ a, float* __restrict__ kr) {
    __shared__ float xo[FVS];
    __shared__ float xs[FVS];
    __shared__ float cc[CDIM];
    int tid = threadIdx.x, lane = tid & 63, wid = tid >> 6;
    if (tid < FVS) xo[tid] = Xold[tid];
    __syncthreads();
    if (tid < FVS) {
        float acc = 0.f;
        #pragma unroll
        for (int i = 0; i < FVS; ++i) acc += xo[i] * red[i * FVS + tid];
        float xn = tanhf(acc);
        xs[tid] = xn;
        if (blockIdx.x == 0) Xnew[tid] = xn;
    }
    __syncthreads();
    {
        float acc = bc[tid];
        const float* wrow = Wc + tid * (FVS + PLEN);
        #pragma unroll
        for (int i = 0; i < FVS; ++i) acc += wrow[i] * xs[i];
        #pragma unroll
        for (int i = 0; i < PLEN; ++i) acc += wrow[FVS + i] * prog_next[i];
        cc[tid] = 1.f / (1.f + expf(-acc));
    }
    __syncthreads();
    const float4 cv = ((const float4*)cc)[lane];
    for (int gw = blockIdx.x * 4 + wid; gw < 4096; gw += 2048)
        keys_row(gw, cv, lane, prog_next, Wk, bk, We, be, Wa, ba, Wrk, brk, k, e, a, kr);
}

// final: X_new = tanh(X_old @ red); out = X_new @ out_emb.  1 block x 256.
__global__ void k_final(const float* __restrict__ Xold, const float* __restrict__ red,
                        const float* __restrict__ out_emb, float* __restrict__ out) {
    __shared__ float xo[FVS];
    __shared__ float xs[FVS];
    int tid = threadIdx.x;
    if (tid < FVS) xo[tid] = Xold[tid];
    __syncthreads();
    if (tid < FVS) {
        float acc = 0.f;
        #pragma unroll
        for (int i = 0; i < FVS; ++i) acc += xo[i] * red[i * FVS + tid];
        xs[tid] = tanhf(acc);
    }
    __syncthreads();
    for (int col = tid; col < NOUT; col += 256) {
        float acc = 0.f;
        #pragma unroll
        for (int i = 0; i < FVS; ++i) acc += xs[i] * out_emb[i * NOUT + col];
        out[col] = acc;
    }
}

// ---------------- launch ----------------

extern "C" void kernel_launch(void* const* d_in, const int* in_sizes, int n_in,
                              void* d_out, int out_size, void* d_ws, size_t ws_size,
                              hipStream_t stream) {
    const float* x        = (const float*)d_in[0];
    const float* program  = (const float*)d_in[1];
    const float* memory0  = (const float*)d_in[2];
    const float* in_emb   = (const float*)d_in[3];
    const float* out_emb  = (const float*)d_in[4];
    const float* Wc       = (const float*)d_in[5];
    const float* bc       = (const float*)d_in[6];
    const float* Wk       = (const float*)d_in[7];
    const float* bk       = (const float*)d_in[8];
    const float* We       = (const float*)d_in[9];
    const float* be       = (const float*)d_in[10];
    const float* Wa       = (const float*)d_in[11];
    const float* ba       = (const float*)d_in[12];
    const float* Wrk      = (const float*)d_in[13];
    const float* brk      = (const float*)d_in[14];
    float* out = (float*)d_out;

    float* ws = (float*)d_ws;
    size_t off = 0;
    float* mem     = ws + off; off += (size_t)M_SLOTS * N_DIM;
    float* partial = ws + off; off += (size_t)NCHUNKS * N_DIM;
    float* stat    = ws + off; off += (size_t)8 * M_SLOTS;
    float* Xb0     = ws + off; off += FVS;
    float* Xb1     = ws + off; off += FVS;
    float* c       = ws + off; off += CDIM;
    float* kv      = ws + off; off += N_DIM;
    float* ev      = ws + off; off += N_DIM;
    float* av      = ws + off; off += N_DIM;
    float* krv     = ws + off; off += N_DIM;
    float* ww      = ws + off; off += M_SLOTS;
    float* wr      = ws + off; off += M_SLOTS;
    float* red     = ws + off; off += N_DIM;
    unsigned int* cnt = (unsigned int*)(ws + off); off += STEPS;

    k_init_ctrl<<<1, 256, 0, stream>>>(x, in_emb, program, Wc, bc, Xb0, c, cnt);
    k_keys4<<<512, 256, 0, stream>>>(c, program, Wk, bk, We, be, Wa, ba, Wrk, brk,
                                     kv, ev, av, krv);

    for (int t = 0; t < STEPS; ++t) {
        const float* src = (t == 0) ? memory0 : mem;

        k_sim8_addr<<<4096, 256, 0, stream>>>(src, kv, krv, av, ev, stat, ww, wr, cnt + t);
        k_update_read<<<dim3(4, NCHUNKS), 256, 0, stream>>>(
            src, mem, ww, wr, ev, av, partial, (t < STEPS - 1) ? 1 : 0);
        k_read_reduce<<<64, 256, 0, stream>>>(partial, red);

        const float* Xcur = (t & 1) ? Xb1 : Xb0;
        float*       Xnxt = (t & 1) ? Xb0 : Xb1;
        if (t < STEPS - 1) {
            k_exec_keys<<<512, 256, 0, stream>>>(
                Xcur, Xnxt, red, program + (t + 1) * PLEN,
                Wc, bc, Wk, bk, We, be, Wa, ba, Wrk, brk,
                kv, ev, av, krv);
        } else {
            k_final<<<1, 256, 0, stream>>>(Xcur, red, out_emb, out);
        }
    }
}

// Round 8
// 1287.469 us; speedup vs baseline: 3.3500x; 3.3500x over previous
//
#include <hip/hip_runtime.h>
#include <math.h>

#define M_SLOTS 8192
#define N_DIM   4096
#define FVS     64
#define PLEN    64
#define CDIM    256
#define NIN     512
#define NOUT    512
#define STEPS   8
#define EPS_F   1e-8f

#define ROWS_PB 32                       // rows per stats/read block
#define NRB     (M_SLOTS / ROWS_PB)      // 256 row-blocks

// ---------------- helpers ----------------

__device__ inline float wave_sum(float v) {
    for (int off = 32; off; off >>= 1) v += __shfl_down(v, off);
    return v;
}

__device__ inline float blk_sum_1024(float v, float* sh) {
    v = wave_sum(v);
    int lane = threadIdx.x & 63, wid = threadIdx.x >> 6;
    if (lane == 0) sh[wid] = v;
    __syncthreads();
    if (threadIdx.x < 16) {
        v = sh[threadIdx.x];
        for (int off = 8; off; off >>= 1) v += __shfl_down(v, off);
        if (threadIdx.x == 0) sh[16] = v;
    }
    __syncthreads();
    float r = sh[16];
    __syncthreads();
    return r;
}

// ---------------- tiny-state kernels ----------------

// X = x @ input_embedding, then c = sigmoid(Wc @ concat(X, prog0) + bc)
__global__ void k_init_ctrl(const float* __restrict__ x, const float* __restrict__ emb,
                            const float* __restrict__ prog0,
                            const float* __restrict__ Wc, const float* __restrict__ bc,
                            float* __restrict__ X, float* __restrict__ c) {
    __shared__ float in[FVS + PLEN];
    int tid = threadIdx.x;  // 256
    if (tid < FVS) {
        float acc = 0.f;
        for (int i = 0; i < NIN; ++i) acc += x[i] * emb[i * FVS + tid];
        X[tid] = acc;
        in[tid] = acc;
    } else if (tid < FVS + PLEN) {
        in[tid] = prog0[tid - FVS];
    }
    __syncthreads();
    float acc = bc[tid];
    const float* wrow = Wc + tid * (FVS + PLEN);
    #pragma unroll 8
    for (int i = 0; i < FVS + PLEN; ++i) acc += wrow[i] * in[i];
    c[tid] = 1.f / (1.f + expf(-acc));
}

// one wave -> one key row (all four outputs)
__device__ inline void keys_row(int gw, float4 cv, int lane, const float* __restrict__ prog,
                                const float* __restrict__ Wk, const float* __restrict__ bk,
                                const float* __restrict__ We, const float* __restrict__ be,
                                const float* __restrict__ Wa, const float* __restrict__ ba,
                                const float* __restrict__ Wrk, const float* __restrict__ brk,
                                float* __restrict__ k, float* __restrict__ e,
                                float* __restrict__ a, float* __restrict__ kr) {
    float4 wv;
    wv = ((const float4*)(Wk + (size_t)gw * CDIM))[lane];
    float sK = wv.x*cv.x + wv.y*cv.y + wv.z*cv.z + wv.w*cv.w;
    wv = ((const float4*)(We + (size_t)gw * CDIM))[lane];
    float sE = wv.x*cv.x + wv.y*cv.y + wv.z*cv.z + wv.w*cv.w;
    wv = ((const float4*)(Wa + (size_t)gw * CDIM))[lane];
    float sA = wv.x*cv.x + wv.y*cv.y + wv.z*cv.z + wv.w*cv.w;
    float sR = Wrk[(size_t)gw * PLEN + lane] * prog[lane];
    sK = wave_sum(sK); sE = wave_sum(sE); sA = wave_sum(sA); sR = wave_sum(sR);
    if (lane == 0) {
        k[gw]  = tanhf(sK + bk[gw]);
        e[gw]  = 1.f / (1.f + expf(-(sE + be[gw])));
        a[gw]  = tanhf(sA + ba[gw]);
        kr[gw] = tanhf(sR + brk[gw]);
    }
}

// standalone keys (step 0).  grid 512 x 256
__global__ __launch_bounds__(256) void k_keys4(
        const float* __restrict__ c, const float* __restrict__ prog,
        const float* __restrict__ Wk, const float* __restrict__ bk,
        const float* __restrict__ We, const float* __restrict__ be,
        const float* __restrict__ Wa, const float* __restrict__ ba,
        const float* __restrict__ Wrk, const float* __restrict__ brk,
        float* __restrict__ k, float* __restrict__ e,
        float* __restrict__ a, float* __restrict__ kr) {
    int lane = threadIdx.x & 63, wid = threadIdx.x >> 6;
    const float4 cv = ((const float4*)c)[lane];
    for (int gw = blockIdx.x * 4 + wid; gw < 4096; gw += 2048)
        keys_row(gw, cv, lane, prog, Wk, bk, We, be, Wa, ba, Wrk, brk, k, e, a, kr);
}

// ---------------- heavy passes (update-replay over clean mem0) ----------------

// Stats pass at step t (NUP = t prior updates applied in registers).
// grid (4, NRB) x 256: block = 1024-col stripe x 32 rows; thread = 1 float4.
// Outputs stat4[cc*8+st][m], st: 0 v.k 1 v.kr 2 v.(e*kr) 3 v.a 4 v.(e*a)
//                                5 v^2  6 v^2.e  7 v^2.e^2   (partial over stripe)
template<int NUP>
__global__ __launch_bounds__(256) void k_stats(
        const float* __restrict__ mem0,
        const float* __restrict__ ehist, const float* __restrict__ ahist,  // [8][N_DIM]
        const float* __restrict__ wwhist,                                  // [8][M_SLOTS]
        const float* __restrict__ kc, const float* __restrict__ krc,
        float* __restrict__ stat4) {
    const int tid  = threadIdx.x;
    const int cc   = blockIdx.x;            // col stripe 0..3
    const int rb   = blockIdx.y;            // row block 0..NRB-1
    const int col4 = cc * 256 + tid;        // float4 col index [0,1024)
    const int HN   = (NUP > 0) ? NUP : 1;
    float4 eh[HN], ah[HN];
    #pragma unroll
    for (int s = 0; s < NUP; ++s) {
        eh[s] = ((const float4*)(ehist + (size_t)s * N_DIM))[col4];
        ah[s] = ((const float4*)(ahist + (size_t)s * N_DIM))[col4];
    }
    const float4 kk = ((const float4*)kc)[col4];
    const float4 rr = ((const float4*)krc)[col4];
    const float4 ce = ((const float4*)(ehist + (size_t)NUP * N_DIM))[col4];
    const float4 ca = ((const float4*)(ahist + (size_t)NUP * N_DIM))[col4];
    __shared__ float shc[4][8];
    const int lane = tid & 63, wid = tid >> 6;
    for (int r = 0; r < ROWS_PB; ++r) {
        const int m = rb * ROWS_PB + r;
        float4 v = ((const float4*)(mem0 + (size_t)m * N_DIM))[col4];
        #pragma unroll
        for (int s = 0; s < NUP; ++s) {
            float w = wwhist[(size_t)s * M_SLOTS + m];
            v.x = v.x * (1.f - w * eh[s].x) + w * ah[s].x;
            v.y = v.y * (1.f - w * eh[s].y) + w * ah[s].y;
            v.z = v.z * (1.f - w * eh[s].z) + w * ah[s].z;
            v.w = v.w * (1.f - w * eh[s].w) + w * ah[s].w;
        }
        float s0=0,s1=0,s2=0,s3=0,s4=0,s5=0,s6=0,s7=0;
        #define ACC1(vv,kc_,rc_,ac_,ec_) { float _v=vv,_k=kc_,_r=rc_,_a=ac_,_e=ec_; \
            float _ve=_v*_e, _v2=_v*_v, _v2e=_v2*_e; \
            s0+=_v*_k; s1+=_v*_r; s2+=_ve*_r; s3+=_v*_a; s4+=_ve*_a; \
            s5+=_v2; s6+=_v2e; s7+=_v2e*_e; }
        ACC1(v.x, kk.x, rr.x, ca.x, ce.x)
        ACC1(v.y, kk.y, rr.y, ca.y, ce.y)
        ACC1(v.z, kk.z, rr.z, ca.z, ce.z)
        ACC1(v.w, kk.w, rr.w, ca.w, ce.w)
        #undef ACC1
        s0=wave_sum(s0); s1=wave_sum(s1); s2=wave_sum(s2); s3=wave_sum(s3);
        s4=wave_sum(s4); s5=wave_sum(s5); s6=wave_sum(s6); s7=wave_sum(s7);
        if (lane == 0) {
            shc[wid][0]=s0; shc[wid][1]=s1; shc[wid][2]=s2; shc[wid][3]=s3;
            shc[wid][4]=s4; shc[wid][5]=s5; shc[wid][6]=s6; shc[wid][7]=s7;
        }
        __syncthreads();
        if (tid < 8) {
            float tot = shc[0][tid] + shc[1][tid] + shc[2][tid] + shc[3][tid];
            stat4[(size_t)(cc * 8 + tid) * M_SLOTS + m] = tot;
        }
        __syncthreads();
    }
}

// Read pass at step t (NUP = t+1 updates applied); partial[rb][col] = sum wr[m]*v.
template<int NUP>
__global__ __launch_bounds__(256) void k_read(
        const float* __restrict__ mem0,
        const float* __restrict__ ehist, const float* __restrict__ ahist,
        const float* __restrict__ wwhist,
        const float* __restrict__ wr,
        float* __restrict__ partial) {
    const int tid  = threadIdx.x;
    const int cc   = blockIdx.x;
    const int rb   = blockIdx.y;
    const int col4 = cc * 256 + tid;
    float4 eh[NUP], ah[NUP];
    #pragma unroll
    for (int s = 0; s < NUP; ++s) {
        eh[s] = ((const float4*)(ehist + (size_t)s * N_DIM))[col4];
        ah[s] = ((const float4*)(ahist + (size_t)s * N_DIM))[col4];
    }
    float4 acc = make_float4(0.f, 0.f, 0.f, 0.f);
    for (int r = 0; r < ROWS_PB; ++r) {
        const int m = rb * ROWS_PB + r;
        float4 v = ((const float4*)(mem0 + (size_t)m * N_DIM))[col4];
        #pragma unroll
        for (int s = 0; s < NUP; ++s) {
            float w = wwhist[(size_t)s * M_SLOTS + m];
            v.x = v.x * (1.f - w * eh[s].x) + w * ah[s].x;
            v.y = v.y * (1.f - w * eh[s].y) + w * ah[s].y;
            v.z = v.z * (1.f - w * eh[s].z) + w * ah[s].z;
            v.w = v.w * (1.f - w * eh[s].w) + w * ah[s].w;
        }
        float w2 = wr[m];
        acc.x += w2 * v.x; acc.y += w2 * v.y; acc.z += w2 * v.z; acc.w += w2 * v.w;
    }
    ((float4*)partial)[(size_t)rb * (N_DIM / 4) + col4] = acc;
}

// Dual addressing from 4-stripe partial stats.  1 block x 1024.
// Writes ww into wwhist slot t, wr into wr_cur.
__global__ __launch_bounds__(1024) void k_addr(
        const float* __restrict__ kc, const float* __restrict__ krc,
        const float* __restrict__ ac,
        const float* __restrict__ stat4,
        float* __restrict__ ww, float* __restrict__ wr) {
    __shared__ float sh[17];
    int tid = threadIdx.x;
    float a0=0, a1=0, a2=0, a3=0;
    for (int i = tid; i < N_DIM; i += 1024) {
        float kv = kc[i], rv = krc[i], av = ac[i];
        a0 += kv*kv; a1 += rv*rv; a2 += av*rv; a3 += av*av;
    }
    float d0 = blk_sum_1024(a0, sh);
    float d1 = blk_sum_1024(a1, sh);
    float d2 = blk_sum_1024(a2, sh);
    float d3 = blk_sum_1024(a3, sh);
    float knorm = sqrtf(d0), krnorm = sqrtf(d1);

    #define ST(st, m) (stat4[(size_t)(st) * M_SLOTS + (m)] \
                     + stat4[(size_t)((st) + 8) * M_SLOTS + (m)] \
                     + stat4[(size_t)((st) + 16) * M_SLOTS + (m)] \
                     + stat4[(size_t)((st) + 24) * M_SLOTS + (m)])
    float ex[M_SLOTS / 1024];
    float n2l[M_SLOTS / 1024];
    float ls = 0.f;
    #pragma unroll
    for (int j = 0; j < M_SLOTS / 1024; ++j) {
        int m = tid + j * 1024;
        float n2 = ST(5, m);
        n2l[j] = n2;
        float v = ST(0, m) / (sqrtf(n2) * knorm + EPS_F);
        ex[j] = expf(v);                 // cosine in [-1,1]: no overflow
        ls += ex[j];
    }
    ls = blk_sum_1024(ls, sh);
    float inv = 1.f / ls;
    float wv[M_SLOTS / 1024];
    #pragma unroll
    for (int j = 0; j < M_SLOTS / 1024; ++j) {
        wv[j] = ex[j] * inv;
        ww[tid + j * 1024] = wv[j];
    }
    float ls2 = 0.f;
    #pragma unroll
    for (int j = 0; j < M_SLOTS / 1024; ++j) {
        int m = tid + j * 1024;
        float w1 = wv[j];
        float sim2 = ST(1, m) - w1 * ST(2, m) + w1 * d2;
        float n2n  = n2l[j] - 2.f*w1*ST(6, m) + w1*w1*ST(7, m)
                   + 2.f*w1*ST(3, m) - 2.f*w1*w1*ST(4, m) + w1*w1*d3;
        float v = sim2 / (sqrtf(n2n) * krnorm + EPS_F);
        ex[j] = expf(v);
        ls2 += ex[j];
    }
    #undef ST
    ls2 = blk_sum_1024(ls2, sh);
    float inv2 = 1.f / ls2;
    #pragma unroll
    for (int j = 0; j < M_SLOTS / 1024; ++j) wr[tid + j * 1024] = ex[j] * inv2;
}

// red[c] = sum over NRB partial rows.  grid 64 x 256.
__global__ void k_read_reduce(const float* __restrict__ partial, float* __restrict__ red) {
    __shared__ float gsh[4][64];
    int l = threadIdx.x & 63;
    int q = threadIdx.x >> 6;
    int c = blockIdx.x * 64 + l;
    float acc = 0.f;
    #pragma unroll 8
    for (int r = q * (NRB / 4); r < (q + 1) * (NRB / 4); ++r)
        acc += partial[(size_t)r * N_DIM + c];
    gsh[q][l] = acc;
    __syncthreads();
    if (threadIdx.x < 64)
        red[blockIdx.x * 64 + threadIdx.x] =
            gsh[0][threadIdx.x] + gsh[1][threadIdx.x] + gsh[2][threadIdx.x] + gsh[3][threadIdx.x];
}

// X_new = tanh(X_old @ red); c = sigmoid(Wc [X_new, prog_next] + bc); next step's keys.
// grid 512 x 256.  Only block 0 writes X_new.
__global__ __launch_bounds__(256) void k_exec_keys(
        const float* __restrict__ Xold, float* __restrict__ Xnew,
        const float* __restrict__ red, const float* __restrict__ prog_next,
        const float* __restrict__ Wc, const float* __restrict__ bc,
        const float* __restrict__ Wk, const float* __restrict__ bk,
        const float* __restrict__ We, const float* __restrict__ be,
        const float* __restrict__ Wa, const float* __restrict__ ba,
        const float* __restrict__ Wrk, const float* __restrict__ brk,
        float* __restrict__ k, float* __restrict__ e,
        float* __restrict__ a, float* __restrict__ kr) {
    __shared__ float xo[FVS];
    __shared__ float xs[FVS];
    __shared__ float cc[CDIM];
    int tid = threadIdx.x, lane = tid & 63, wid = tid >> 6;
    if (tid < FVS) xo[tid] = Xold[tid];
    __syncthreads();
    if (tid < FVS) {
        float acc = 0.f;
        #pragma unroll
        for (int i = 0; i < FVS; ++i) acc += xo[i] * red[i * FVS + tid];
        float xn = tanhf(acc);
        xs[tid] = xn;
        if (blockIdx.x == 0) Xnew[tid] = xn;
    }
    __syncthreads();
    {
        float acc = bc[tid];
        const float* wrow = Wc + tid * (FVS + PLEN);
        #pragma unroll
        for (int i = 0; i < FVS; ++i) acc += wrow[i] * xs[i];
        #pragma unroll
        for (int i = 0; i < PLEN; ++i) acc += wrow[FVS + i] * prog_next[i];
        cc[tid] = 1.f / (1.f + expf(-acc));
    }
    __syncthreads();
    const float4 cv = ((const float4*)cc)[lane];
    for (int gw = blockIdx.x * 4 + wid; gw < 4096; gw += 2048)
        keys_row(gw, cv, lane, prog_next, Wk, bk, We, be, Wa, ba, Wrk, brk, k, e, a, kr);
}

// final: X_new = tanh(X_old @ red); out = X_new @ out_emb.  1 block x 256.
__global__ void k_final(const float* __restrict__ Xold, const float* __restrict__ red,
                        const float* __restrict__ out_emb, float* __restrict__ out) {
    __shared__ float xo[FVS];
    __shared__ float xs[FVS];
    int tid = threadIdx.x;
    if (tid < FVS) xo[tid] = Xold[tid];
    __syncthreads();
    if (tid < FVS) {
        float acc = 0.f;
        #pragma unroll
        for (int i = 0; i < FVS; ++i) acc += xo[i] * red[i * FVS + tid];
        xs[tid] = tanhf(acc);
    }
    __syncthreads();
    for (int col = tid; col < NOUT; col += 256) {
        float acc = 0.f;
        #pragma unroll
        for (int i = 0; i < FVS; ++i) acc += xs[i] * out_emb[i * NOUT + col];
        out[col] = acc;
    }
}

// ---------------- launch ----------------

typedef void (*stats_fn)(const float*, const float*, const float*, const float*,
                         const float*, const float*, float*);
typedef void (*read_fn)(const float*, const float*, const float*, const float*,
                        const float*, float*);

extern "C" void kernel_launch(void* const* d_in, const int* in_sizes, int n_in,
                              void* d_out, int out_size, void* d_ws, size_t ws_size,
                              hipStream_t stream) {
    const float* x        = (const float*)d_in[0];
    const float* program  = (const float*)d_in[1];
    const float* memory0  = (const float*)d_in[2];
    const float* in_emb   = (const float*)d_in[3];
    const float* out_emb  = (const float*)d_in[4];
    const float* Wc       = (const float*)d_in[5];
    const float* bc       = (const float*)d_in[6];
    const float* Wk       = (const float*)d_in[7];
    const float* bk       = (const float*)d_in[8];
    const float* We       = (const float*)d_in[9];
    const float* be       = (const float*)d_in[10];
    const float* Wa       = (const float*)d_in[11];
    const float* ba       = (const float*)d_in[12];
    const float* Wrk      = (const float*)d_in[13];
    const float* brk      = (const float*)d_in[14];
    float* out = (float*)d_out;

    float* ws = (float*)d_ws;
    size_t off = 0;
    float* ehist   = ws + off; off += (size_t)STEPS * N_DIM;
    float* ahist   = ws + off; off += (size_t)STEPS * N_DIM;
    float* wwhist  = ws + off; off += (size_t)STEPS * M_SLOTS;
    float* kcur    = ws + off; off += N_DIM;
    float* krcur   = ws + off; off += N_DIM;
    float* stat4   = ws + off; off += (size_t)32 * M_SLOTS;
    float* partial = ws + off; off += (size_t)NRB * N_DIM;
    float* wrcur   = ws + off; off += M_SLOTS;
    float* red     = ws + off; off += N_DIM;
    float* Xb0     = ws + off; off += FVS;
    float* Xb1     = ws + off; off += FVS;
    float* c       = ws + off; off += CDIM;

    static const stats_fn SF[STEPS] = {
        k_stats<0>, k_stats<1>, k_stats<2>, k_stats<3>,
        k_stats<4>, k_stats<5>, k_stats<6>, k_stats<7> };
    static const read_fn RF[STEPS] = {
        k_read<1>, k_read<2>, k_read<3>, k_read<4>,
        k_read<5>, k_read<6>, k_read<7>, k_read<8> };

    k_init_ctrl<<<1, 256, 0, stream>>>(x, in_emb, program, Wc, bc, Xb0, c);
    k_keys4<<<512, 256, 0, stream>>>(c, program, Wk, bk, We, be, Wa, ba, Wrk, brk,
                                     kcur, ehist, ahist, krcur);

    for (int t = 0; t < STEPS; ++t) {
        // stats of mem_t (replayed from mem0) with current keys
        SF[t]<<<dim3(4, NRB), 256, 0, stream>>>(
            memory0, ehist, ahist, wwhist, kcur, krcur, stat4);
        // dual softmax addressing -> ww (slot t), wr
        k_addr<<<1, 1024, 0, stream>>>(kcur, krcur, ahist + (size_t)t * N_DIM,
                                       stat4, wwhist + (size_t)t * M_SLOTS, wrcur);
        // read pass: replay updates 0..t, weight by wr
        RF[t]<<<dim3(4, NRB), 256, 0, stream>>>(
            memory0, ehist, ahist, wwhist, wrcur, partial);
        k_read_reduce<<<64, 256, 0, stream>>>(partial, red);

        const float* Xcur = (t & 1) ? Xb1 : Xb0;
        float*       Xnxt = (t & 1) ? Xb0 : Xb1;
        if (t < STEPS - 1) {
            k_exec_keys<<<512, 256, 0, stream>>>(
                Xcur, Xnxt, red, program + (t + 1) * PLEN,
                Wc, bc, Wk, bk, We, be, Wa, ba, Wrk, brk,
                kcur, ehist + (size_t)(t + 1) * N_DIM,
                ahist + (size_t)(t + 1) * N_DIM, krcur);
        } else {
            k_final<<<1, 256, 0, stream>>>(Xcur, red, out_emb, out);
        }
    }
}

// Round 9
// 1170.988 us; speedup vs baseline: 3.6832x; 1.0995x over previous
//
#include <hip/hip_runtime.h>
#include <math.h>

#define M_SLOTS 8192
#define N_DIM   4096
#define FVS     64
#define PLEN    64
#define CDIM    256
#define NIN     512
#define NOUT    512
#define STEPS   8
#define EPS_F   1e-8f

#define SROWS   16                       // rows per stats block
#define NSB     (M_SLOTS / SROWS)        // 512 stats row-chunks
#define RROWS   32                       // rows per read block
#define NRB     (M_SLOTS / RROWS)        // 256 read row-chunks

// ---------------- helpers ----------------

__device__ inline float wave_sum(float v) {
    for (int off = 32; off; off >>= 1) v += __shfl_down(v, off);
    return v;
}

__device__ inline float blk_sum_1024(float v, float* sh) {
    v = wave_sum(v);
    int lane = threadIdx.x & 63, wid = threadIdx.x >> 6;
    if (lane == 0) sh[wid] = v;
    __syncthreads();
    if (threadIdx.x < 16) {
        v = sh[threadIdx.x];
        for (int off = 8; off; off >>= 1) v += __shfl_down(v, off);
        if (threadIdx.x == 0) sh[16] = v;
    }
    __syncthreads();
    float r = sh[16];
    __syncthreads();
    return r;
}

// ---------------- tiny-state kernels ----------------

// X = x @ input_embedding, then c = sigmoid(Wc @ concat(X, prog0) + bc)
__global__ void k_init_ctrl(const float* __restrict__ x, const float* __restrict__ emb,
                            const float* __restrict__ prog0,
                            const float* __restrict__ Wc, const float* __restrict__ bc,
                            float* __restrict__ X, float* __restrict__ c) {
    __shared__ float in[FVS + PLEN];
    int tid = threadIdx.x;  // 256
    if (tid < FVS) {
        float acc = 0.f;
        for (int i = 0; i < NIN; ++i) acc += x[i] * emb[i * FVS + tid];
        X[tid] = acc;
        in[tid] = acc;
    } else if (tid < FVS + PLEN) {
        in[tid] = prog0[tid - FVS];
    }
    __syncthreads();
    float acc = bc[tid];
    const float* wrow = Wc + tid * (FVS + PLEN);
    #pragma unroll 8
    for (int i = 0; i < FVS + PLEN; ++i) acc += wrow[i] * in[i];
    c[tid] = 1.f / (1.f + expf(-acc));
}

// one wave -> one key row (all four outputs)
__device__ inline void keys_row(int gw, float4 cv, int lane, const float* __restrict__ prog,
                                const float* __restrict__ Wk, const float* __restrict__ bk,
                                const float* __restrict__ We, const float* __restrict__ be,
                                const float* __restrict__ Wa, const float* __restrict__ ba,
                                const float* __restrict__ Wrk, const float* __restrict__ brk,
                                float* __restrict__ k, float* __restrict__ e,
                                float* __restrict__ a, float* __restrict__ kr) {
    float4 wv;
    wv = ((const float4*)(Wk + (size_t)gw * CDIM))[lane];
    float sK = wv.x*cv.x + wv.y*cv.y + wv.z*cv.z + wv.w*cv.w;
    wv = ((const float4*)(We + (size_t)gw * CDIM))[lane];
    float sE = wv.x*cv.x + wv.y*cv.y + wv.z*cv.z + wv.w*cv.w;
    wv = ((const float4*)(Wa + (size_t)gw * CDIM))[lane];
    float sA = wv.x*cv.x + wv.y*cv.y + wv.z*cv.z + wv.w*cv.w;
    float sR = Wrk[(size_t)gw * PLEN + lane] * prog[lane];
    sK = wave_sum(sK); sE = wave_sum(sE); sA = wave_sum(sA); sR = wave_sum(sR);
    if (lane == 0) {
        k[gw]  = tanhf(sK + bk[gw]);
        e[gw]  = 1.f / (1.f + expf(-(sE + be[gw])));
        a[gw]  = tanhf(sA + ba[gw]);
        kr[gw] = tanhf(sR + brk[gw]);
    }
}

// standalone keys (step 0).  grid 512 x 256
__global__ __launch_bounds__(256) void k_keys4(
        const float* __restrict__ c, const float* __restrict__ prog,
        const float* __restrict__ Wk, const float* __restrict__ bk,
        const float* __restrict__ We, const float* __restrict__ be,
        const float* __restrict__ Wa, const float* __restrict__ ba,
        const float* __restrict__ Wrk, const float* __restrict__ brk,
        float* __restrict__ k, float* __restrict__ e,
        float* __restrict__ a, float* __restrict__ kr) {
    int lane = threadIdx.x & 63, wid = threadIdx.x >> 6;
    const float4 cv = ((const float4*)c)[lane];
    for (int gw = blockIdx.x * 4 + wid; gw < 4096; gw += 2048)
        keys_row(gw, cv, lane, prog, Wk, bk, We, be, Wa, ba, Wrk, brk, k, e, a, kr);
}

// ---------------- heavy passes (update-replay over clean mem0) ----------------

// Stats pass at step t (NUP prior updates replayed in registers).
// grid (4, NSB) x 256; block = 1024-col stripe x 16 rows; thread = 1 float4 col slot.
// NO barrier in the row loop: per row, 8 wave_sums then lane0 -> private LDS slot.
// stat4[(cc*8+st)*M + m], st: 0 v.k 1 v.kr 2 v.(e*kr) 3 v.a 4 v.(e*a)
//                              5 v^2  6 v^2.e  7 v^2.e^2   (partial over stripe)
template<int NUP>
__global__ __launch_bounds__(256) void k_stats(
        const float* __restrict__ mem0,
        const float* __restrict__ ehist, const float* __restrict__ ahist,  // [8][N_DIM]
        const float* __restrict__ wwhist,                                  // [8][M_SLOTS]
        const float* __restrict__ kc, const float* __restrict__ krc,
        float* __restrict__ stat4) {
    const int tid  = threadIdx.x;
    const int cc   = blockIdx.x;            // col stripe 0..3
    const int rb   = blockIdx.y;            // row chunk 0..NSB-1
    const int col4 = cc * 256 + tid;        // float4 col index [0,1024)
    const int lane = tid & 63, wid = tid >> 6;
    const int HN   = (NUP > 0) ? NUP : 1;
    float4 eh[HN], ah[HN];
    #pragma unroll
    for (int s = 0; s < NUP; ++s) {
        eh[s] = ((const float4*)(ehist + (size_t)s * N_DIM))[col4];
        ah[s] = ((const float4*)(ahist + (size_t)s * N_DIM))[col4];
    }
    const float4 kk = ((const float4*)kc)[col4];
    const float4 rr = ((const float4*)krc)[col4];
    const float4 ce = ((const float4*)(ehist + (size_t)NUP * N_DIM))[col4];
    const float4 ca = ((const float4*)(ahist + (size_t)NUP * N_DIM))[col4];

    __shared__ float shc[4][SROWS][8];

    #pragma unroll
    for (int r = 0; r < SROWS; ++r) {
        const int m = rb * SROWS + r;
        float4 v = ((const float4*)(mem0 + (size_t)m * N_DIM))[col4];
        #pragma unroll
        for (int s = 0; s < NUP; ++s) {
            float w = wwhist[(size_t)s * M_SLOTS + m];
            v.x = v.x * (1.f - w * eh[s].x) + w * ah[s].x;
            v.y = v.y * (1.f - w * eh[s].y) + w * ah[s].y;
            v.z = v.z * (1.f - w * eh[s].z) + w * ah[s].z;
            v.w = v.w * (1.f - w * eh[s].w) + w * ah[s].w;
        }
        float s0=0,s1=0,s2=0,s3=0,s4=0,s5=0,s6=0,s7=0;
        #define ACC1(vv,kc_,rc_,ac_,ec_) { float _v=vv,_k=kc_,_r=rc_,_a=ac_,_e=ec_; \
            float _ve=_v*_e, _v2=_v*_v, _v2e=_v2*_e; \
            s0+=_v*_k; s1+=_v*_r; s2+=_ve*_r; s3+=_v*_a; s4+=_ve*_a; \
            s5+=_v2; s6+=_v2e; s7+=_v2e*_e; }
        ACC1(v.x, kk.x, rr.x, ca.x, ce.x)
        ACC1(v.y, kk.y, rr.y, ca.y, ce.y)
        ACC1(v.z, kk.z, rr.z, ca.z, ce.z)
        ACC1(v.w, kk.w, rr.w, ca.w, ce.w)
        #undef ACC1
        s0=wave_sum(s0); s1=wave_sum(s1); s2=wave_sum(s2); s3=wave_sum(s3);
        s4=wave_sum(s4); s5=wave_sum(s5); s6=wave_sum(s6); s7=wave_sum(s7);
        if (lane == 0) {
            shc[wid][r][0]=s0; shc[wid][r][1]=s1; shc[wid][r][2]=s2; shc[wid][r][3]=s3;
            shc[wid][r][4]=s4; shc[wid][r][5]=s5; shc[wid][r][6]=s6; shc[wid][r][7]=s7;
        }
    }
    __syncthreads();
    if (tid < SROWS * 8) {
        const int r = tid >> 3, st = tid & 7;
        float tot = shc[0][r][st] + shc[1][r][st] + shc[2][r][st] + shc[3][r][st];
        stat4[(size_t)(cc * 8 + st) * M_SLOTS + rb * SROWS + r] = tot;
    }
}

// Read pass at step t (NUP = t+1 updates applied); partial[rb][col] = sum wr[m]*v.
// grid (4, NRB) x 256; no barriers, hist in regs.
template<int NUP>
__global__ __launch_bounds__(256) void k_read(
        const float* __restrict__ mem0,
        const float* __restrict__ ehist, const float* __restrict__ ahist,
        const float* __restrict__ wwhist,
        const float* __restrict__ wr,
        float* __restrict__ partial) {
    const int tid  = threadIdx.x;
    const int cc   = blockIdx.x;
    const int rb   = blockIdx.y;
    const int col4 = cc * 256 + tid;
    float4 eh[NUP], ah[NUP];
    #pragma unroll
    for (int s = 0; s < NUP; ++s) {
        eh[s] = ((const float4*)(ehist + (size_t)s * N_DIM))[col4];
        ah[s] = ((const float4*)(ahist + (size_t)s * N_DIM))[col4];
    }
    float4 acc = make_float4(0.f, 0.f, 0.f, 0.f);
    for (int r = 0; r < RROWS; ++r) {
        const int m = rb * RROWS + r;
        float4 v = ((const float4*)(mem0 + (size_t)m * N_DIM))[col4];
        #pragma unroll
        for (int s = 0; s < NUP; ++s) {
            float w = wwhist[(size_t)s * M_SLOTS + m];
            v.x = v.x * (1.f - w * eh[s].x) + w * ah[s].x;
            v.y = v.y * (1.f - w * eh[s].y) + w * ah[s].y;
            v.z = v.z * (1.f - w * eh[s].z) + w * ah[s].z;
            v.w = v.w * (1.f - w * eh[s].w) + w * ah[s].w;
        }
        float w2 = wr[m];
        acc.x += w2 * v.x; acc.y += w2 * v.y; acc.z += w2 * v.z; acc.w += w2 * v.w;
    }
    ((float4*)partial)[(size_t)rb * (N_DIM / 4) + col4] = acc;
}

// Dual addressing from 4-stripe partial stats.  1 block x 1024.
__global__ __launch_bounds__(1024) void k_addr(
        const float* __restrict__ kc, const float* __restrict__ krc,
        const float* __restrict__ ac,
        const float* __restrict__ stat4,
        float* __restrict__ ww, float* __restrict__ wr) {
    __shared__ float sh[17];
    int tid = threadIdx.x;
    float a0=0, a1=0, a2=0, a3=0;
    for (int i = tid; i < N_DIM; i += 1024) {
        float kv = kc[i], rv = krc[i], av = ac[i];
        a0 += kv*kv; a1 += rv*rv; a2 += av*rv; a3 += av*av;
    }
    float d0 = blk_sum_1024(a0, sh);
    float d1 = blk_sum_1024(a1, sh);
    float d2 = blk_sum_1024(a2, sh);
    float d3 = blk_sum_1024(a3, sh);
    float knorm = sqrtf(d0), krnorm = sqrtf(d1);

    #define ST(st, m) (stat4[(size_t)(st) * M_SLOTS + (m)] \
                     + stat4[(size_t)((st) + 8) * M_SLOTS + (m)] \
                     + stat4[(size_t)((st) + 16) * M_SLOTS + (m)] \
                     + stat4[(size_t)((st) + 24) * M_SLOTS + (m)])
    float ex[M_SLOTS / 1024];
    float n2l[M_SLOTS / 1024];
    float ls = 0.f;
    #pragma unroll
    for (int j = 0; j < M_SLOTS / 1024; ++j) {
        int m = tid + j * 1024;
        float n2 = ST(5, m);
        n2l[j] = n2;
        float v = ST(0, m) / (sqrtf(n2) * knorm + EPS_F);
        ex[j] = expf(v);                 // cosine in [-1,1]: no overflow
        ls += ex[j];
    }
    ls = blk_sum_1024(ls, sh);
    float inv = 1.f / ls;
    float wv[M_SLOTS / 1024];
    #pragma unroll
    for (int j = 0; j < M_SLOTS / 1024; ++j) {
        wv[j] = ex[j] * inv;
        ww[tid + j * 1024] = wv[j];
    }
    float ls2 = 0.f;
    #pragma unroll
    for (int j = 0; j < M_SLOTS / 1024; ++j) {
        int m = tid + j * 1024;
        float w1 = wv[j];
        float sim2 = ST(1, m) - w1 * ST(2, m) + w1 * d2;
        float n2n  = n2l[j] - 2.f*w1*ST(6, m) + w1*w1*ST(7, m)
                   + 2.f*w1*ST(3, m) - 2.f*w1*w1*ST(4, m) + w1*w1*d3;
        float v = sim2 / (sqrtf(n2n) * krnorm + EPS_F);
        ex[j] = expf(v);
        ls2 += ex[j];
    }
    #undef ST
    ls2 = blk_sum_1024(ls2, sh);
    float inv2 = 1.f / ls2;
    #pragma unroll
    for (int j = 0; j < M_SLOTS / 1024; ++j) wr[tid + j * 1024] = ex[j] * inv2;
}

// red[c] = sum over NRB partial rows.  grid 64 x 256.
__global__ void k_read_reduce(const float* __restrict__ partial, float* __restrict__ red) {
    __shared__ float gsh[4][64];
    int l = threadIdx.x & 63;
    int q = threadIdx.x >> 6;
    int c = blockIdx.x * 64 + l;
    float acc = 0.f;
    #pragma unroll 8
    for (int r = q * (NRB / 4); r < (q + 1) * (NRB / 4); ++r)
        acc += partial[(size_t)r * N_DIM + c];
    gsh[q][l] = acc;
    __syncthreads();
    if (threadIdx.x < 64)
        red[blockIdx.x * 64 + threadIdx.x] =
            gsh[0][threadIdx.x] + gsh[1][threadIdx.x] + gsh[2][threadIdx.x] + gsh[3][threadIdx.x];
}

// X_new = tanh(X_old @ red); c = sigmoid(Wc [X_new, prog_next] + bc); next step's keys.
// grid 512 x 256.  Only block 0 writes X_new.
__global__ __launch_bounds__(256) void k_exec_keys(
        const float* __restrict__ Xold, float* __restrict__ Xnew,
        const float* __restrict__ red, const float* __restrict__ prog_next,
        const float* __restrict__ Wc, const float* __restrict__ bc,
        const float* __restrict__ Wk, const float* __restrict__ bk,
        const float* __restrict__ We, const float* __restrict__ be,
        const float* __restrict__ Wa, const float* __restrict__ ba,
        const float* __restrict__ Wrk, const float* __restrict__ brk,
        float* __restrict__ k, float* __restrict__ e,
        float* __restrict__ a, float* __restrict__ kr) {
    __shared__ float xo[FVS];
    __shared__ float xs[FVS];
    __shared__ float cc[CDIM];
    int tid = threadIdx.x, lane = tid & 63, wid = tid >> 6;
    if (tid < FVS) xo[tid] = Xold[tid];
    __syncthreads();
    if (tid < FVS) {
        float acc = 0.f;
        #pragma unroll
        for (int i = 0; i < FVS; ++i) acc += xo[i] * red[i * FVS + tid];
        float xn = tanhf(acc);
        xs[tid] = xn;
        if (blockIdx.x == 0) Xnew[tid] = xn;
    }
    __syncthreads();
    {
        float acc = bc[tid];
        const float* wrow = Wc + tid * (FVS + PLEN);
        #pragma unroll
        for (int i = 0; i < FVS; ++i) acc += wrow[i] * xs[i];
        #pragma unroll
        for (int i = 0; i < PLEN; ++i) acc += wrow[FVS + i] * prog_next[i];
        cc[tid] = 1.f / (1.f + expf(-acc));
    }
    __syncthreads();
    const float4 cv = ((const float4*)cc)[lane];
    for (int gw = blockIdx.x * 4 + wid; gw < 4096; gw += 2048)
        keys_row(gw, cv, lane, prog_next, Wk, bk, We, be, Wa, ba, Wrk, brk, k, e, a, kr);
}

// final: X_new = tanh(X_old @ red); out = X_new @ out_emb.  1 block x 256.
__global__ void k_final(const float* __restrict__ Xold, const float* __restrict__ red,
                        const float* __restrict__ out_emb, float* __restrict__ out) {
    __shared__ float xo[FVS];
    __shared__ float xs[FVS];
    int tid = threadIdx.x;
    if (tid < FVS) xo[tid] = Xold[tid];
    __syncthreads();
    if (tid < FVS) {
        float acc = 0.f;
        #pragma unroll
        for (int i = 0; i < FVS; ++i) acc += xo[i] * red[i * FVS + tid];
        xs[tid] = tanhf(acc);
    }
    __syncthreads();
    for (int col = tid; col < NOUT; col += 256) {
        float acc = 0.f;
        #pragma unroll
        for (int i = 0; i < FVS; ++i) acc += xs[i] * out_emb[i * NOUT + col];
        out[col] = acc;
    }
}

// ---------------- launch ----------------

typedef void (*stats_fn)(const float*, const float*, const float*, const float*,
                         const float*, const float*, float*);
typedef void (*read_fn)(const float*, const float*, const float*, const float*,
                        const float*, float*);

extern "C" void kernel_launch(void* const* d_in, const int* in_sizes, int n_in,
                              void* d_out, int out_size, void* d_ws, size_t ws_size,
                              hipStream_t stream) {
    const float* x        = (const float*)d_in[0];
    const float* program  = (const float*)d_in[1];
    const float* memory0  = (const float*)d_in[2];
    const float* in_emb   = (const float*)d_in[3];
    const float* out_emb  = (const float*)d_in[4];
    const float* Wc       = (const float*)d_in[5];
    const float* bc       = (const float*)d_in[6];
    const float* Wk       = (const float*)d_in[7];
    const float* bk       = (const float*)d_in[8];
    const float* We       = (const float*)d_in[9];
    const float* be       = (const float*)d_in[10];
    const float* Wa       = (const float*)d_in[11];
    const float* ba       = (const float*)d_in[12];
    const float* Wrk      = (const float*)d_in[13];
    const float* brk      = (const float*)d_in[14];
    float* out = (float*)d_out;

    float* ws = (float*)d_ws;
    size_t off = 0;
    float* ehist   = ws + off; off += (size_t)STEPS * N_DIM;
    float* ahist   = ws + off; off += (size_t)STEPS * N_DIM;
    float* wwhist  = ws + off; off += (size_t)STEPS * M_SLOTS;
    float* kcur    = ws + off; off += N_DIM;
    float* krcur   = ws + off; off += N_DIM;
    float* stat4   = ws + off; off += (size_t)32 * M_SLOTS;
    float* partial = ws + off; off += (size_t)NRB * N_DIM;
    float* wrcur   = ws + off; off += M_SLOTS;
    float* red     = ws + off; off += N_DIM;
    float* Xb0     = ws + off; off += FVS;
    float* Xb1     = ws + off; off += FVS;
    float* c       = ws + off; off += CDIM;

    static const stats_fn SF[STEPS] = {
        k_stats<0>, k_stats<1>, k_stats<2>, k_stats<3>,
        k_stats<4>, k_stats<5>, k_stats<6>, k_stats<7> };
    static const read_fn RF[STEPS] = {
        k_read<1>, k_read<2>, k_read<3>, k_read<4>,
        k_read<5>, k_read<6>, k_read<7>, k_read<8> };

    k_init_ctrl<<<1, 256, 0, stream>>>(x, in_emb, program, Wc, bc, Xb0, c);
    k_keys4<<<512, 256, 0, stream>>>(c, program, Wk, bk, We, be, Wa, ba, Wrk, brk,
                                     kcur, ehist, ahist, krcur);

    for (int t = 0; t < STEPS; ++t) {
        // stats of mem_t (replayed from mem0) with current keys
        SF[t]<<<dim3(4, NSB), 256, 0, stream>>>(
            memory0, ehist, ahist, wwhist, kcur, krcur, stat4);
        // dual softmax addressing -> ww (slot t), wr
        k_addr<<<1, 1024, 0, stream>>>(kcur, krcur, ahist + (size_t)t * N_DIM,
                                       stat4, wwhist + (size_t)t * M_SLOTS, wrcur);
        // read pass: replay updates 0..t, weight by wr
        RF[t]<<<dim3(4, NRB), 256, 0, stream>>>(
            memory0, ehist, ahist, wwhist, wrcur, partial);
        k_read_reduce<<<64, 256, 0, stream>>>(partial, red);

        const float* Xcur = (t & 1) ? Xb1 : Xb0;
        float*       Xnxt = (t & 1) ? Xb0 : Xb1;
        if (t < STEPS - 1) {
            k_exec_keys<<<512, 256, 0, stream>>>(
                Xcur, Xnxt, red, program + (t + 1) * PLEN,
                Wc, bc, Wk, bk, We, be, Wa, ba, Wrk, brk,
                kcur, ehist + (size_t)(t + 1) * N_DIM,
                ahist + (size_t)(t + 1) * N_DIM, krcur);
        } else {
            k_final<<<1, 256, 0, stream>>>(Xcur, red, out_emb, out);
        }
    }
}

// Round 10
// 791.124 us; speedup vs baseline: 5.4517x; 1.4802x over previous
//
#include <hip/hip_runtime.h>
#include <math.h>

#define M_SLOTS 8192
#define N_DIM   4096
#define FVS     64
#define PLEN    64
#define CDIM    256
#define NIN     512
#define NOUT    512
#define STEPS   8
#define EPS_F   1e-8f

#define SROWS   32                       // rows per stats block
#define NSB     (M_SLOTS / SROWS)        // 256 stats row-chunks
#define RROWS   32                       // rows per read block
#define NRB     (M_SLOTS / RROWS)        // 256 read row-chunks

// ---------------- helpers ----------------

__device__ inline float wave_sum(float v) {
    for (int off = 32; off; off >>= 1) v += __shfl_down(v, off);
    return v;
}

__device__ inline float blk_sum_1024(float v, float* sh) {
    v = wave_sum(v);
    int lane = threadIdx.x & 63, wid = threadIdx.x >> 6;
    if (lane == 0) sh[wid] = v;
    __syncthreads();
    if (threadIdx.x < 16) {
        v = sh[threadIdx.x];
        for (int off = 8; off; off >>= 1) v += __shfl_down(v, off);
        if (threadIdx.x == 0) sh[16] = v;
    }
    __syncthreads();
    float r = sh[16];
    __syncthreads();
    return r;
}

// Reduce-scatter butterfly: 8 per-lane values -> full wave sums, 10 shfls total.
// On return, lane l (l<8, and each 8-lane group) holds stat  4*(l&1) | (l&2) | ((l>>2)&1).
__device__ inline void wave_reduce8(float v[8], int lane) {
    float t0, t1, t2, t3;
    t0 = __shfl_xor((lane & 1) ? v[0] : v[4], 1);
    t1 = __shfl_xor((lane & 1) ? v[1] : v[5], 1);
    t2 = __shfl_xor((lane & 1) ? v[2] : v[6], 1);
    t3 = __shfl_xor((lane & 1) ? v[3] : v[7], 1);
    v[0] = ((lane & 1) ? v[4] : v[0]) + t0;
    v[1] = ((lane & 1) ? v[5] : v[1]) + t1;
    v[2] = ((lane & 1) ? v[6] : v[2]) + t2;
    v[3] = ((lane & 1) ? v[7] : v[3]) + t3;
    t0 = __shfl_xor((lane & 2) ? v[0] : v[2], 2);
    t1 = __shfl_xor((lane & 2) ? v[1] : v[3], 2);
    v[0] = ((lane & 2) ? v[2] : v[0]) + t0;
    v[1] = ((lane & 2) ? v[3] : v[1]) + t1;
    t0 = __shfl_xor((lane & 4) ? v[0] : v[1], 4);
    v[0] = ((lane & 4) ? v[1] : v[0]) + t0;
    v[0] += __shfl_xor(v[0], 8);
    v[0] += __shfl_xor(v[0], 16);
    v[0] += __shfl_xor(v[0], 32);
}

// ---------------- tiny-state kernels ----------------

// X = x @ input_embedding, then c = sigmoid(Wc @ concat(X, prog0) + bc)
__global__ void k_init_ctrl(const float* __restrict__ x, const float* __restrict__ emb,
                            const float* __restrict__ prog0,
                            const float* __restrict__ Wc, const float* __restrict__ bc,
                            float* __restrict__ X, float* __restrict__ c) {
    __shared__ float in[FVS + PLEN];
    int tid = threadIdx.x;  // 256
    if (tid < FVS) {
        float acc = 0.f;
        for (int i = 0; i < NIN; ++i) acc += x[i] * emb[i * FVS + tid];
        X[tid] = acc;
        in[tid] = acc;
    } else if (tid < FVS + PLEN) {
        in[tid] = prog0[tid - FVS];
    }
    __syncthreads();
    float acc = bc[tid];
    const float* wrow = Wc + tid * (FVS + PLEN);
    #pragma unroll 8
    for (int i = 0; i < FVS + PLEN; ++i) acc += wrow[i] * in[i];
    c[tid] = 1.f / (1.f + expf(-acc));
}

// one wave -> one key row (all four outputs)
__device__ inline void keys_row(int gw, float4 cv, int lane, const float* __restrict__ prog,
                                const float* __restrict__ Wk, const float* __restrict__ bk,
                                const float* __restrict__ We, const float* __restrict__ be,
                                const float* __restrict__ Wa, const float* __restrict__ ba,
                                const float* __restrict__ Wrk, const float* __restrict__ brk,
                                float* __restrict__ k, float* __restrict__ e,
                                float* __restrict__ a, float* __restrict__ kr) {
    float4 wv;
    wv = ((const float4*)(Wk + (size_t)gw * CDIM))[lane];
    float sK = wv.x*cv.x + wv.y*cv.y + wv.z*cv.z + wv.w*cv.w;
    wv = ((const float4*)(We + (size_t)gw * CDIM))[lane];
    float sE = wv.x*cv.x + wv.y*cv.y + wv.z*cv.z + wv.w*cv.w;
    wv = ((const float4*)(Wa + (size_t)gw * CDIM))[lane];
    float sA = wv.x*cv.x + wv.y*cv.y + wv.z*cv.z + wv.w*cv.w;
    float sR = Wrk[(size_t)gw * PLEN + lane] * prog[lane];
    sK = wave_sum(sK); sE = wave_sum(sE); sA = wave_sum(sA); sR = wave_sum(sR);
    if (lane == 0) {
        k[gw]  = tanhf(sK + bk[gw]);
        e[gw]  = 1.f / (1.f + expf(-(sE + be[gw])));
        a[gw]  = tanhf(sA + ba[gw]);
        kr[gw] = tanhf(sR + brk[gw]);
    }
}

// standalone keys (step 0).  grid 512 x 256
__global__ __launch_bounds__(256) void k_keys4(
        const float* __restrict__ c, const float* __restrict__ prog,
        const float* __restrict__ Wk, const float* __restrict__ bk,
        const float* __restrict__ We, const float* __restrict__ be,
        const float* __restrict__ Wa, const float* __restrict__ ba,
        const float* __restrict__ Wrk, const float* __restrict__ brk,
        float* __restrict__ k, float* __restrict__ e,
        float* __restrict__ a, float* __restrict__ kr) {
    int lane = threadIdx.x & 63, wid = threadIdx.x >> 6;
    const float4 cv = ((const float4*)c)[lane];
    for (int gw = blockIdx.x * 4 + wid; gw < 4096; gw += 2048)
        keys_row(gw, cv, lane, prog, Wk, bk, We, be, Wa, ba, Wrk, brk, k, e, a, kr);
}

// ---------------- heavy passes (update-replay over clean mem0) ----------------

// Stats pass at step t (NUP prior updates replayed in registers).
// grid (4, NSB) x 256; block = 1024-col stripe x SROWS rows; thread = 1 float4 slot.
// Per row: 1 float4 load + replay + reduce-scatter butterfly (10 shfl), lane<8 -> LDS.
// stat4[(cc*8+st)*M + m], st: 0 v.k 1 v.kr 2 v.(e*kr) 3 v.a 4 v.(e*a)
//                              5 v^2  6 v^2.e  7 v^2.e^2   (partial over stripe)
template<int NUP>
__global__ __launch_bounds__(256) void k_stats(
        const float* __restrict__ mem0,
        const float* __restrict__ ehist, const float* __restrict__ ahist,  // [8][N_DIM]
        const float* __restrict__ wwhist,                                  // [8][M_SLOTS]
        const float* __restrict__ kc, const float* __restrict__ krc,
        float* __restrict__ stat4) {
    const int tid  = threadIdx.x;
    const int cc   = blockIdx.x;            // col stripe 0..3
    const int rb   = blockIdx.y;            // row chunk 0..NSB-1
    const int col4 = cc * 256 + tid;        // float4 col index [0,1024)
    const int lane = tid & 63, wid = tid >> 6;
    const int HN   = (NUP > 0) ? NUP : 1;
    float4 eh[HN], ah[HN];
    #pragma unroll
    for (int s = 0; s < NUP; ++s) {
        eh[s] = ((const float4*)(ehist + (size_t)s * N_DIM))[col4];
        ah[s] = ((const float4*)(ahist + (size_t)s * N_DIM))[col4];
    }
    const float4 kk = ((const float4*)kc)[col4];
    const float4 rr = ((const float4*)krc)[col4];
    const float4 ce = ((const float4*)(ehist + (size_t)NUP * N_DIM))[col4];
    const float4 ca = ((const float4*)(ahist + (size_t)NUP * N_DIM))[col4];

    __shared__ float shc[4][SROWS][8];

    #pragma unroll
    for (int r = 0; r < SROWS; ++r) {
        const int m = rb * SROWS + r;
        float4 v = ((const float4*)(mem0 + (size_t)m * N_DIM))[col4];
        #pragma unroll
        for (int s = 0; s < NUP; ++s) {
            float w = wwhist[(size_t)s * M_SLOTS + m];
            v.x = v.x * (1.f - w * eh[s].x) + w * ah[s].x;
            v.y = v.y * (1.f - w * eh[s].y) + w * ah[s].y;
            v.z = v.z * (1.f - w * eh[s].z) + w * ah[s].z;
            v.w = v.w * (1.f - w * eh[s].w) + w * ah[s].w;
        }
        float sv[8] = {0.f, 0.f, 0.f, 0.f, 0.f, 0.f, 0.f, 0.f};
        #define ACC1(vv,kc_,rc_,ac_,ec_) { float _v=vv,_k=kc_,_r=rc_,_a=ac_,_e=ec_; \
            float _ve=_v*_e, _v2=_v*_v, _v2e=_v2*_e; \
            sv[0]+=_v*_k; sv[1]+=_v*_r; sv[2]+=_ve*_r; sv[3]+=_v*_a; sv[4]+=_ve*_a; \
            sv[5]+=_v2; sv[6]+=_v2e; sv[7]+=_v2e*_e; }
        ACC1(v.x, kk.x, rr.x, ca.x, ce.x)
        ACC1(v.y, kk.y, rr.y, ca.y, ce.y)
        ACC1(v.z, kk.z, rr.z, ca.z, ce.z)
        ACC1(v.w, kk.w, rr.w, ca.w, ce.w)
        #undef ACC1
        wave_reduce8(sv, lane);
        if (lane < 8) {
            const int st = ((lane & 1) << 2) | (lane & 2) | ((lane >> 2) & 1);
            shc[wid][r][st] = sv[0];
        }
    }
    __syncthreads();
    // 256 threads = SROWS*8 slots: one thread folds 4 wave-partials of one (row,stat)
    {
        const int r = tid >> 3, st = tid & 7;
        float tot = shc[0][r][st] + shc[1][r][st] + shc[2][r][st] + shc[3][r][st];
        stat4[(size_t)(cc * 8 + st) * M_SLOTS + rb * SROWS + r] = tot;
    }
}

// Read pass at step t (NUP = t+1 updates applied); partial[rb][col] = sum wr[m]*v.
// grid (4, NRB) x 256; no barriers, hist in regs.
template<int NUP>
__global__ __launch_bounds__(256) void k_read(
        const float* __restrict__ mem0,
        const float* __restrict__ ehist, const float* __restrict__ ahist,
        const float* __restrict__ wwhist,
        const float* __restrict__ wr,
        float* __restrict__ partial) {
    const int tid  = threadIdx.x;
    const int cc   = blockIdx.x;
    const int rb   = blockIdx.y;
    const int col4 = cc * 256 + tid;
    float4 eh[NUP], ah[NUP];
    #pragma unroll
    for (int s = 0; s < NUP; ++s) {
        eh[s] = ((const float4*)(ehist + (size_t)s * N_DIM))[col4];
        ah[s] = ((const float4*)(ahist + (size_t)s * N_DIM))[col4];
    }
    float4 acc = make_float4(0.f, 0.f, 0.f, 0.f);
    for (int r = 0; r < RROWS; ++r) {
        const int m = rb * RROWS + r;
        float4 v = ((const float4*)(mem0 + (size_t)m * N_DIM))[col4];
        #pragma unroll
        for (int s = 0; s < NUP; ++s) {
            float w = wwhist[(size_t)s * M_SLOTS + m];
            v.x = v.x * (1.f - w * eh[s].x) + w * ah[s].x;
            v.y = v.y * (1.f - w * eh[s].y) + w * ah[s].y;
            v.z = v.z * (1.f - w * eh[s].z) + w * ah[s].z;
            v.w = v.w * (1.f - w * eh[s].w) + w * ah[s].w;
        }
        float w2 = wr[m];
        acc.x += w2 * v.x; acc.y += w2 * v.y; acc.z += w2 * v.z; acc.w += w2 * v.w;
    }
    ((float4*)partial)[(size_t)rb * (N_DIM / 4) + col4] = acc;
}

// Dual addressing from 4-stripe partial stats.  1 block x 1024.
__global__ __launch_bounds__(1024) void k_addr(
        const float* __restrict__ kc, const float* __restrict__ krc,
        const float* __restrict__ ac,
        const float* __restrict__ stat4,
        float* __restrict__ ww, float* __restrict__ wr) {
    __shared__ float sh[17];
    int tid = threadIdx.x;
    float a0=0, a1=0, a2=0, a3=0;
    for (int i = tid; i < N_DIM; i += 1024) {
        float kv = kc[i], rv = krc[i], av = ac[i];
        a0 += kv*kv; a1 += rv*rv; a2 += av*rv; a3 += av*av;
    }
    float d0 = blk_sum_1024(a0, sh);
    float d1 = blk_sum_1024(a1, sh);
    float d2 = blk_sum_1024(a2, sh);
    float d3 = blk_sum_1024(a3, sh);
    float knorm = sqrtf(d0), krnorm = sqrtf(d1);

    #define ST(st, m) (stat4[(size_t)(st) * M_SLOTS + (m)] \
                     + stat4[(size_t)((st) + 8) * M_SLOTS + (m)] \
                     + stat4[(size_t)((st) + 16) * M_SLOTS + (m)] \
                     + stat4[(size_t)((st) + 24) * M_SLOTS + (m)])
    float ex[M_SLOTS / 1024];
    float n2l[M_SLOTS / 1024];
    float ls = 0.f;
    #pragma unroll
    for (int j = 0; j < M_SLOTS / 1024; ++j) {
        int m = tid + j * 1024;
        float n2 = ST(5, m);
        n2l[j] = n2;
        float v = ST(0, m) / (sqrtf(n2) * knorm + EPS_F);
        ex[j] = expf(v);                 // cosine in [-1,1]: no overflow
        ls += ex[j];
    }
    ls = blk_sum_1024(ls, sh);
    float inv = 1.f / ls;
    float wv[M_SLOTS / 1024];
    #pragma unroll
    for (int j = 0; j < M_SLOTS / 1024; ++j) {
        wv[j] = ex[j] * inv;
        ww[tid + j * 1024] = wv[j];
    }
    float ls2 = 0.f;
    #pragma unroll
    for (int j = 0; j < M_SLOTS / 1024; ++j) {
        int m = tid + j * 1024;
        float w1 = wv[j];
        float sim2 = ST(1, m) - w1 * ST(2, m) + w1 * d2;
        float n2n  = n2l[j] - 2.f*w1*ST(6, m) + w1*w1*ST(7, m)
                   + 2.f*w1*ST(3, m) - 2.f*w1*w1*ST(4, m) + w1*w1*d3;
        float v = sim2 / (sqrtf(n2n) * krnorm + EPS_F);
        ex[j] = expf(v);
        ls2 += ex[j];
    }
    #undef ST
    ls2 = blk_sum_1024(ls2, sh);
    float inv2 = 1.f / ls2;
    #pragma unroll
    for (int j = 0; j < M_SLOTS / 1024; ++j) wr[tid + j * 1024] = ex[j] * inv2;
}

// red[c] = sum over NRB partial rows.  grid 64 x 256.
__global__ void k_read_reduce(const float* __restrict__ partial, float* __restrict__ red) {
    __shared__ float gsh[4][64];
    int l = threadIdx.x & 63;
    int q = threadIdx.x >> 6;
    int c = blockIdx.x * 64 + l;
    float acc = 0.f;
    #pragma unroll 8
    for (int r = q * (NRB / 4); r < (q + 1) * (NRB / 4); ++r)
        acc += partial[(size_t)r * N_DIM + c];
    gsh[q][l] = acc;
    __syncthreads();
    if (threadIdx.x < 64)
        red[blockIdx.x * 64 + threadIdx.x] =
            gsh[0][threadIdx.x] + gsh[1][threadIdx.x] + gsh[2][threadIdx.x] + gsh[3][threadIdx.x];
}

// X_new = tanh(X_old @ red); c = sigmoid(Wc [X_new, prog_next] + bc); next step's keys.
// grid 512 x 256.  Only block 0 writes X_new.
__global__ __launch_bounds__(256) void k_exec_keys(
        const float* __restrict__ Xold, float* __restrict__ Xnew,
        const float* __restrict__ red, const float* __restrict__ prog_next,
        const float* __restrict__ Wc, const float* __restrict__ bc,
        const float* __restrict__ Wk, const float* __restrict__ bk,
        const float* __restrict__ We, const float* __restrict__ be,
        const float* __restrict__ Wa, const float* __restrict__ ba,
        const float* __restrict__ Wrk, const float* __restrict__ brk,
        float* __restrict__ k, float* __restrict__ e,
        float* __restrict__ a, float* __restrict__ kr) {
    __shared__ float xo[FVS];
    __shared__ float xs[FVS];
    __shared__ float cc[CDIM];
    int tid = threadIdx.x, lane = tid & 63, wid = tid >> 6;
    if (tid < FVS) xo[tid] = Xold[tid];
    __syncthreads();
    if (tid < FVS) {
        float acc = 0.f;
        #pragma unroll
        for (int i = 0; i < FVS; ++i) acc += xo[i] * red[i * FVS + tid];
        float xn = tanhf(acc);
        xs[tid] = xn;
        if (blockIdx.x == 0) Xnew[tid] = xn;
    }
    __syncthreads();
    {
        float acc = bc[tid];
        const float* wrow = Wc + tid * (FVS + PLEN);
        #pragma unroll
        for (int i = 0; i < FVS; ++i) acc += wrow[i] * xs[i];
        #pragma unroll
        for (int i = 0; i < PLEN; ++i) acc += wrow[FVS + i] * prog_next[i];
        cc[tid] = 1.f / (1.f + expf(-acc));
    }
    __syncthreads();
    const float4 cv = ((const float4*)cc)[lane];
    for (int gw = blockIdx.x * 4 + wid; gw < 4096; gw += 2048)
        keys_row(gw, cv, lane, prog_next, Wk, bk, We, be, Wa, ba, Wrk, brk, k, e, a, kr);
}

// final: X_new = tanh(X_old @ red); out = X_new @ out_emb.  1 block x 256.
__global__ void k_final(const float* __restrict__ Xold, const float* __restrict__ red,
                        const float* __restrict__ out_emb, float* __restrict__ out) {
    __shared__ float xo[FVS];
    __shared__ float xs[FVS];
    int tid = threadIdx.x;
    if (tid < FVS) xo[tid] = Xold[tid];
    __syncthreads();
    if (tid < FVS) {
        float acc = 0.f;
        #pragma unroll
        for (int i = 0; i < FVS; ++i) acc += xo[i] * red[i * FVS + tid];
        xs[tid] = tanhf(acc);
    }
    __syncthreads();
    for (int col = tid; col < NOUT; col += 256) {
        float acc = 0.f;
        #pragma unroll
        for (int i = 0; i < FVS; ++i) acc += xs[i] * out_emb[i * NOUT + col];
        out[col] = acc;
    }
}

// ---------------- launch ----------------

typedef void (*stats_fn)(const float*, const float*, const float*, const float*,
                         const float*, const float*, float*);
typedef void (*read_fn)(const float*, const float*, const float*, const float*,
                        const float*, float*);

extern "C" void kernel_launch(void* const* d_in, const int* in_sizes, int n_in,
                              void* d_out, int out_size, void* d_ws, size_t ws_size,
                              hipStream_t stream) {
    const float* x        = (const float*)d_in[0];
    const float* program  = (const float*)d_in[1];
    const float* memory0  = (const float*)d_in[2];
    const float* in_emb   = (const float*)d_in[3];
    const float* out_emb  = (const float*)d_in[4];
    const float* Wc       = (const float*)d_in[5];
    const float* bc       = (const float*)d_in[6];
    const float* Wk       = (const float*)d_in[7];
    const float* bk       = (const float*)d_in[8];
    const float* We       = (const float*)d_in[9];
    const float* be       = (const float*)d_in[10];
    const float* Wa       = (const float*)d_in[11];
    const float* ba       = (const float*)d_in[12];
    const float* Wrk      = (const float*)d_in[13];
    const float* brk      = (const float*)d_in[14];
    float* out = (float*)d_out;

    float* ws = (float*)d_ws;
    size_t off = 0;
    float* ehist   = ws + off; off += (size_t)STEPS * N_DIM;
    float* ahist   = ws + off; off += (size_t)STEPS * N_DIM;
    float* wwhist  = ws + off; off += (size_t)STEPS * M_SLOTS;
    float* kcur    = ws + off; off += N_DIM;
    float* krcur   = ws + off; off += N_DIM;
    float* stat4   = ws + off; off += (size_t)32 * M_SLOTS;
    float* partial = ws + off; off += (size_t)NRB * N_DIM;
    float* wrcur   = ws + off; off += M_SLOTS;
    float* red     = ws + off; off += N_DIM;
    float* Xb0     = ws + off; off += FVS;
    float* Xb1     = ws + off; off += FVS;
    float* c       = ws + off; off += CDIM;

    static const stats_fn SF[STEPS] = {
        k_stats<0>, k_stats<1>, k_stats<2>, k_stats<3>,
        k_stats<4>, k_stats<5>, k_stats<6>, k_stats<7> };
    static const read_fn RF[STEPS] = {
        k_read<1>, k_read<2>, k_read<3>, k_read<4>,
        k_read<5>, k_read<6>, k_read<7>, k_read<8> };

    k_init_ctrl<<<1, 256, 0, stream>>>(x, in_emb, program, Wc, bc, Xb0, c);
    k_keys4<<<512, 256, 0, stream>>>(c, program, Wk, bk, We, be, Wa, ba, Wrk, brk,
                                     kcur, ehist, ahist, krcur);

    for (int t = 0; t < STEPS; ++t) {
        // stats of mem_t (replayed from mem0) with current keys
        SF[t]<<<dim3(4, NSB), 256, 0, stream>>>(
            memory0, ehist, ahist, wwhist, kcur, krcur, stat4);
        // dual softmax addressing -> ww (slot t), wr
        k_addr<<<1, 1024, 0, stream>>>(kcur, krcur, ahist + (size_t)t * N_DIM,
                                       stat4, wwhist + (size_t)t * M_SLOTS, wrcur);
        // read pass: replay updates 0..t, weight by wr
        RF[t]<<<dim3(4, NRB), 256, 0, stream>>>(
            memory0, ehist, ahist, wwhist, wrcur, partial);
        k_read_reduce<<<64, 256, 0, stream>>>(partial, red);

        const float* Xcur = (t & 1) ? Xb1 : Xb0;
        float*       Xnxt = (t & 1) ? Xb0 : Xb1;
        if (t < STEPS - 1) {
            k_exec_keys<<<512, 256, 0, stream>>>(
                Xcur, Xnxt, red, program + (t + 1) * PLEN,
                Wc, bc, Wk, bk, We, be, Wa, ba, Wrk, brk,
                kcur, ehist + (size_t)(t + 1) * N_DIM,
                ahist + (size_t)(t + 1) * N_DIM, krcur);
        } else {
            k_final<<<1, 256, 0, stream>>>(Xcur, red, out_emb, out);
        }
    }
}

// Round 11
// 778.012 us; speedup vs baseline: 5.5436x; 1.0169x over previous
//
#include <hip/hip_runtime.h>
#include <math.h>

#define M_SLOTS 8192
#define N_DIM   4096
#define FVS     64
#define PLEN    64
#define CDIM    256
#define NIN     512
#define NOUT    512
#define STEPS   8
#define EPS_F   1e-8f

#define SROWS   32                       // rows per stats block
#define NSB     (M_SLOTS / SROWS)        // 256 stats row-chunks
#define RROWS   32                       // rows per read block
#define NRB     (M_SLOTS / RROWS)        // 256 read row-chunks

// ---------------- helpers ----------------

__device__ inline float wave_sum(float v) {
    for (int off = 32; off; off >>= 1) v += __shfl_down(v, off);
    return v;
}

__device__ inline float blk_sum_1024(float v, float* sh) {
    v = wave_sum(v);
    int lane = threadIdx.x & 63, wid = threadIdx.x >> 6;
    if (lane == 0) sh[wid] = v;
    __syncthreads();
    if (threadIdx.x < 16) {
        v = sh[threadIdx.x];
        for (int off = 8; off; off >>= 1) v += __shfl_down(v, off);
        if (threadIdx.x == 0) sh[16] = v;
    }
    __syncthreads();
    float r = sh[16];
    __syncthreads();
    return r;
}

// Reduce-scatter within 8-lane groups: 8 per-lane values -> per-group sums, 7 shfls.
// On return, every lane holds (in v[0]) its 8-lane group's sum of stat
// st(lane) = ((lane&1)<<2) | (lane&2) | ((lane&4)>>2).
__device__ inline void group_reduce8(float v[8], int lane) {
    float t0, t1, t2, t3;
    t0 = __shfl_xor((lane & 1) ? v[0] : v[4], 1);
    t1 = __shfl_xor((lane & 1) ? v[1] : v[5], 1);
    t2 = __shfl_xor((lane & 1) ? v[2] : v[6], 1);
    t3 = __shfl_xor((lane & 1) ? v[3] : v[7], 1);
    v[0] = ((lane & 1) ? v[4] : v[0]) + t0;
    v[1] = ((lane & 1) ? v[5] : v[1]) + t1;
    v[2] = ((lane & 1) ? v[6] : v[2]) + t2;
    v[3] = ((lane & 1) ? v[7] : v[3]) + t3;
    t0 = __shfl_xor((lane & 2) ? v[0] : v[2], 2);
    t1 = __shfl_xor((lane & 2) ? v[1] : v[3], 2);
    v[0] = ((lane & 2) ? v[2] : v[0]) + t0;
    v[1] = ((lane & 2) ? v[3] : v[1]) + t1;
    t0 = __shfl_xor((lane & 4) ? v[0] : v[1], 4);
    v[0] = ((lane & 4) ? v[1] : v[0]) + t0;
}

// ---------------- tiny-state kernels ----------------

// X = x @ input_embedding, then c = sigmoid(Wc @ concat(X, prog0) + bc)
__global__ void k_init_ctrl(const float* __restrict__ x, const float* __restrict__ emb,
                            const float* __restrict__ prog0,
                            const float* __restrict__ Wc, const float* __restrict__ bc,
                            float* __restrict__ X, float* __restrict__ c) {
    __shared__ float in[FVS + PLEN];
    int tid = threadIdx.x;  // 256
    if (tid < FVS) {
        float acc = 0.f;
        for (int i = 0; i < NIN; ++i) acc += x[i] * emb[i * FVS + tid];
        X[tid] = acc;
        in[tid] = acc;
    } else if (tid < FVS + PLEN) {
        in[tid] = prog0[tid - FVS];
    }
    __syncthreads();
    float acc = bc[tid];
    const float* wrow = Wc + tid * (FVS + PLEN);
    #pragma unroll 8
    for (int i = 0; i < FVS + PLEN; ++i) acc += wrow[i] * in[i];
    c[tid] = 1.f / (1.f + expf(-acc));
}

// one wave -> one key row; writes k, e, a, kr plus fused ekr=e*kr, ea=e*a, e2=e*e
__device__ inline void keys_row(int gw, float4 cv, int lane, const float* __restrict__ prog,
                                const float* __restrict__ Wk, const float* __restrict__ bk,
                                const float* __restrict__ We, const float* __restrict__ be,
                                const float* __restrict__ Wa, const float* __restrict__ ba,
                                const float* __restrict__ Wrk, const float* __restrict__ brk,
                                float* __restrict__ k, float* __restrict__ e,
                                float* __restrict__ a, float* __restrict__ kr,
                                float* __restrict__ ekr, float* __restrict__ ea,
                                float* __restrict__ e2) {
    float4 wv;
    wv = ((const float4*)(Wk + (size_t)gw * CDIM))[lane];
    float sK = wv.x*cv.x + wv.y*cv.y + wv.z*cv.z + wv.w*cv.w;
    wv = ((const float4*)(We + (size_t)gw * CDIM))[lane];
    float sE = wv.x*cv.x + wv.y*cv.y + wv.z*cv.z + wv.w*cv.w;
    wv = ((const float4*)(Wa + (size_t)gw * CDIM))[lane];
    float sA = wv.x*cv.x + wv.y*cv.y + wv.z*cv.z + wv.w*cv.w;
    float sR = Wrk[(size_t)gw * PLEN + lane] * prog[lane];
    sK = wave_sum(sK); sE = wave_sum(sE); sA = wave_sum(sA); sR = wave_sum(sR);
    if (lane == 0) {
        float ev  = 1.f / (1.f + expf(-(sE + be[gw])));
        float av  = tanhf(sA + ba[gw]);
        float krv = tanhf(sR + brk[gw]);
        k[gw]   = tanhf(sK + bk[gw]);
        e[gw]   = ev;
        a[gw]   = av;
        kr[gw]  = krv;
        ekr[gw] = ev * krv;
        ea[gw]  = ev * av;
        e2[gw]  = ev * ev;
    }
}

// standalone keys (step 0).  grid 512 x 256
__global__ __launch_bounds__(256) void k_keys4(
        const float* __restrict__ c, const float* __restrict__ prog,
        const float* __restrict__ Wk, const float* __restrict__ bk,
        const float* __restrict__ We, const float* __restrict__ be,
        const float* __restrict__ Wa, const float* __restrict__ ba,
        const float* __restrict__ Wrk, const float* __restrict__ brk,
        float* __restrict__ k, float* __restrict__ e,
        float* __restrict__ a, float* __restrict__ kr,
        float* __restrict__ ekr, float* __restrict__ ea, float* __restrict__ e2) {
    int lane = threadIdx.x & 63, wid = threadIdx.x >> 6;
    const float4 cv = ((const float4*)c)[lane];
    for (int gw = blockIdx.x * 4 + wid; gw < 4096; gw += 2048)
        keys_row(gw, cv, lane, prog, Wk, bk, We, be, Wa, ba, Wrk, brk,
                 k, e, a, kr, ekr, ea, e2);
}

// ---------------- heavy passes (update-replay over clean mem0) ----------------

// Stats pass at step t (NUP prior updates replayed in registers).
// grid (4, NSB) x 256; block = 1024-col stripe x SROWS rows; thread = 1 float4 slot.
// Per row: 1 float4 load + replay + 9 VALU/elem stats + 7-shfl group reduce,
// all 64 lanes -> LDS slot [wid][r][g*8+st].  One barrier per block.
// stat4[(cc*8+st)*M + m], st: 0 v.k 1 v.kr 2 v.ekr 3 v.a 4 v.ea
//                              5 v^2  6 v^2.e  7 v^2.e2   (partial over stripe)
template<int NUP>
__global__ __launch_bounds__(256) void k_stats(
        const float* __restrict__ mem0,
        const float* __restrict__ ehist, const float* __restrict__ ahist,  // [8][N_DIM]
        const float* __restrict__ wwhist,                                  // [8][M_SLOTS]
        const float* __restrict__ kc, const float* __restrict__ krc,
        const float* __restrict__ ekrc, const float* __restrict__ eac,
        const float* __restrict__ e2c,
        float* __restrict__ stat4) {
    const int tid  = threadIdx.x;
    const int cc   = blockIdx.x;            // col stripe 0..3
    const int rb   = blockIdx.y;            // row chunk 0..NSB-1
    const int col4 = cc * 256 + tid;        // float4 col index [0,1024)
    const int lane = tid & 63, wid = tid >> 6;
    const int HN   = (NUP > 0) ? NUP : 1;
    float4 eh[HN], ah[HN];
    #pragma unroll
    for (int s = 0; s < NUP; ++s) {
        eh[s] = ((const float4*)(ehist + (size_t)s * N_DIM))[col4];
        ah[s] = ((const float4*)(ahist + (size_t)s * N_DIM))[col4];
    }
    const float4 kk  = ((const float4*)kc)[col4];
    const float4 rr  = ((const float4*)krc)[col4];
    const float4 fkr = ((const float4*)ekrc)[col4];
    const float4 fea = ((const float4*)eac)[col4];
    const float4 fe2 = ((const float4*)e2c)[col4];
    const float4 ce  = ((const float4*)(ehist + (size_t)NUP * N_DIM))[col4];
    const float4 ca  = ((const float4*)(ahist + (size_t)NUP * N_DIM))[col4];

    __shared__ float shc[4][SROWS][64];

    #pragma unroll
    for (int r = 0; r < SROWS; ++r) {
        const int m = rb * SROWS + r;
        float4 v = ((const float4*)(mem0 + (size_t)m * N_DIM))[col4];
        #pragma unroll
        for (int s = 0; s < NUP; ++s) {
            float w = wwhist[(size_t)s * M_SLOTS + m];
            v.x = v.x * (1.f - w * eh[s].x) + w * ah[s].x;
            v.y = v.y * (1.f - w * eh[s].y) + w * ah[s].y;
            v.z = v.z * (1.f - w * eh[s].z) + w * ah[s].z;
            v.w = v.w * (1.f - w * eh[s].w) + w * ah[s].w;
        }
        float sv[8] = {0.f, 0.f, 0.f, 0.f, 0.f, 0.f, 0.f, 0.f};
        #define ACC1(vv,kc_,rc_,ekr_,ac_,ea_,ec_,e2_) { \
            float _v = vv; float _v2 = _v * _v; \
            sv[0] += _v * kc_;  sv[1] += _v * rc_;  sv[2] += _v * ekr_; \
            sv[3] += _v * ac_;  sv[4] += _v * ea_;  sv[5] += _v * _v; \
            sv[6] += _v2 * ec_; sv[7] += _v2 * e2_; }
        ACC1(v.x, kk.x, rr.x, fkr.x, ca.x, fea.x, ce.x, fe2.x)
        ACC1(v.y, kk.y, rr.y, fkr.y, ca.y, fea.y, ce.y, fe2.y)
        ACC1(v.z, kk.z, rr.z, fkr.z, ca.z, fea.z, ce.z, fe2.z)
        ACC1(v.w, kk.w, rr.w, fkr.w, ca.w, fea.w, ce.w, fe2.w)
        #undef ACC1
        group_reduce8(sv, lane);
        {
            const int st = ((lane & 1) << 2) | (lane & 2) | ((lane & 4) >> 2);
            shc[wid][r][(lane & 56) + st] = sv[0];
        }
    }
    __syncthreads();
    // 256 threads: one thread folds 4 waves x 8 groups of one (row, stat)
    {
        const int r = tid >> 3, st = tid & 7;
        float tot = 0.f;
        #pragma unroll
        for (int w = 0; w < 4; ++w)
            #pragma unroll
            for (int g = 0; g < 8; ++g)
                tot += shc[w][r][g * 8 + st];
        stat4[(size_t)(cc * 8 + st) * M_SLOTS + rb * SROWS + r] = tot;
    }
}

// Read pass at step t (NUP = t+1 updates applied); partial[rb][col] = sum wr[m]*v.
// grid (4, NRB) x 256; no barriers, hist in regs.
template<int NUP>
__global__ __launch_bounds__(256) void k_read(
        const float* __restrict__ mem0,
        const float* __restrict__ ehist, const float* __restrict__ ahist,
        const float* __restrict__ wwhist,
        const float* __restrict__ wr,
        float* __restrict__ partial) {
    const int tid  = threadIdx.x;
    const int cc   = blockIdx.x;
    const int rb   = blockIdx.y;
    const int col4 = cc * 256 + tid;
    float4 eh[NUP], ah[NUP];
    #pragma unroll
    for (int s = 0; s < NUP; ++s) {
        eh[s] = ((const float4*)(ehist + (size_t)s * N_DIM))[col4];
        ah[s] = ((const float4*)(ahist + (size_t)s * N_DIM))[col4];
    }
    float4 acc = make_float4(0.f, 0.f, 0.f, 0.f);
    for (int r = 0; r < RROWS; ++r) {
        const int m = rb * RROWS + r;
        float4 v = ((const float4*)(mem0 + (size_t)m * N_DIM))[col4];
        #pragma unroll
        for (int s = 0; s < NUP; ++s) {
            float w = wwhist[(size_t)s * M_SLOTS + m];
            v.x = v.x * (1.f - w * eh[s].x) + w * ah[s].x;
            v.y = v.y * (1.f - w * eh[s].y) + w * ah[s].y;
            v.z = v.z * (1.f - w * eh[s].z) + w * ah[s].z;
            v.w = v.w * (1.f - w * eh[s].w) + w * ah[s].w;
        }
        float w2 = wr[m];
        acc.x += w2 * v.x; acc.y += w2 * v.y; acc.z += w2 * v.z; acc.w += w2 * v.w;
    }
    ((float4*)partial)[(size_t)rb * (N_DIM / 4) + col4] = acc;
}

// Dual addressing from 4-stripe partial stats.  1 block x 1024.
__global__ __launch_bounds__(1024) void k_addr(
        const float* __restrict__ kc, const float* __restrict__ krc,
        const float* __restrict__ ac,
        const float* __restrict__ stat4,
        float* __restrict__ ww, float* __restrict__ wr) {
    __shared__ float sh[17];
    int tid = threadIdx.x;
    float a0=0, a1=0, a2=0, a3=0;
    for (int i = tid; i < N_DIM; i += 1024) {
        float kv = kc[i], rv = krc[i], av = ac[i];
        a0 += kv*kv; a1 += rv*rv; a2 += av*rv; a3 += av*av;
    }
    float d0 = blk_sum_1024(a0, sh);
    float d1 = blk_sum_1024(a1, sh);
    float d2 = blk_sum_1024(a2, sh);
    float d3 = blk_sum_1024(a3, sh);
    float knorm = sqrtf(d0), krnorm = sqrtf(d1);

    #define ST(st, m) (stat4[(size_t)(st) * M_SLOTS + (m)] \
                     + stat4[(size_t)((st) + 8) * M_SLOTS + (m)] \
                     + stat4[(size_t)((st) + 16) * M_SLOTS + (m)] \
                     + stat4[(size_t)((st) + 24) * M_SLOTS + (m)])
    float ex[M_SLOTS / 1024];
    float n2l[M_SLOTS / 1024];
    float ls = 0.f;
    #pragma unroll
    for (int j = 0; j < M_SLOTS / 1024; ++j) {
        int m = tid + j * 1024;
        float n2 = ST(5, m);
        n2l[j] = n2;
        float v = ST(0, m) / (sqrtf(n2) * knorm + EPS_F);
        ex[j] = expf(v);                 // cosine in [-1,1]: no overflow
        ls += ex[j];
    }
    ls = blk_sum_1024(ls, sh);
    float inv = 1.f / ls;
    float wv[M_SLOTS / 1024];
    #pragma unroll
    for (int j = 0; j < M_SLOTS / 1024; ++j) {
        wv[j] = ex[j] * inv;
        ww[tid + j * 1024] = wv[j];
    }
    float ls2 = 0.f;
    #pragma unroll
    for (int j = 0; j < M_SLOTS / 1024; ++j) {
        int m = tid + j * 1024;
        float w1 = wv[j];
        float sim2 = ST(1, m) - w1 * ST(2, m) + w1 * d2;
        float n2n  = n2l[j] - 2.f*w1*ST(6, m) + w1*w1*ST(7, m)
                   + 2.f*w1*ST(3, m) - 2.f*w1*w1*ST(4, m) + w1*w1*d3;
        float v = sim2 / (sqrtf(n2n) * krnorm + EPS_F);
        ex[j] = expf(v);
        ls2 += ex[j];
    }
    #undef ST
    ls2 = blk_sum_1024(ls2, sh);
    float inv2 = 1.f / ls2;
    #pragma unroll
    for (int j = 0; j < M_SLOTS / 1024; ++j) wr[tid + j * 1024] = ex[j] * inv2;
}

// red[c] = sum over NRB partial rows.  grid 64 x 256.
__global__ void k_read_reduce(const float* __restrict__ partial, float* __restrict__ red) {
    __shared__ float gsh[4][64];
    int l = threadIdx.x & 63;
    int q = threadIdx.x >> 6;
    int c = blockIdx.x * 64 + l;
    float acc = 0.f;
    #pragma unroll 8
    for (int r = q * (NRB / 4); r < (q + 1) * (NRB / 4); ++r)
        acc += partial[(size_t)r * N_DIM + c];
    gsh[q][l] = acc;
    __syncthreads();
    if (threadIdx.x < 64)
        red[blockIdx.x * 64 + threadIdx.x] =
            gsh[0][threadIdx.x] + gsh[1][threadIdx.x] + gsh[2][threadIdx.x] + gsh[3][threadIdx.x];
}

// X_new = tanh(X_old @ red); c = sigmoid(Wc [X_new, prog_next] + bc); next step's keys.
// grid 512 x 256.  Only block 0 writes X_new.
__global__ __launch_bounds__(256) void k_exec_keys(
        const float* __restrict__ Xold, float* __restrict__ Xnew,
        const float* __restrict__ red, const float* __restrict__ prog_next,
        const float* __restrict__ Wc, const float* __restrict__ bc,
        const float* __restrict__ Wk, const float* __restrict__ bk,
        const float* __restrict__ We, const float* __restrict__ be,
        const float* __restrict__ Wa, const float* __restrict__ ba,
        const float* __restrict__ Wrk, const float* __restrict__ brk,
        float* __restrict__ k, float* __restrict__ e,
        float* __restrict__ a, float* __restrict__ kr,
        float* __restrict__ ekr, float* __restrict__ ea, float* __restrict__ e2) {
    __shared__ float xo[FVS];
    __shared__ float xs[FVS];
    __shared__ float cc[CDIM];
    int tid = threadIdx.x, lane = tid & 63, wid = tid >> 6;
    if (tid < FVS) xo[tid] = Xold[tid];
    __syncthreads();
    if (tid < FVS) {
        float acc = 0.f;
        #pragma unroll
        for (int i = 0; i < FVS; ++i) acc += xo[i] * red[i * FVS + tid];
        float xn = tanhf(acc);
        xs[tid] = xn;
        if (blockIdx.x == 0) Xnew[tid] = xn;
    }
    __syncthreads();
    {
        float acc = bc[tid];
        const float* wrow = Wc + tid * (FVS + PLEN);
        #pragma unroll
        for (int i = 0; i < FVS; ++i) acc += wrow[i] * xs[i];
        #pragma unroll
        for (int i = 0; i < PLEN; ++i) acc += wrow[FVS + i] * prog_next[i];
        cc[tid] = 1.f / (1.f + expf(-acc));
    }
    __syncthreads();
    const float4 cv = ((const float4*)cc)[lane];
    for (int gw = blockIdx.x * 4 + wid; gw < 4096; gw += 2048)
        keys_row(gw, cv, lane, prog_next, Wk, bk, We, be, Wa, ba, Wrk, brk,
                 k, e, a, kr, ekr, ea, e2);
}

// final: X_new = tanh(X_old @ red); out = X_new @ out_emb.  1 block x 256.
__global__ void k_final(const float* __restrict__ Xold, const float* __restrict__ red,
                        const float* __restrict__ out_emb, float* __restrict__ out) {
    __shared__ float xo[FVS];
    __shared__ float xs[FVS];
    int tid = threadIdx.x;
    if (tid < FVS) xo[tid] = Xold[tid];
    __syncthreads();
    if (tid < FVS) {
        float acc = 0.f;
        #pragma unroll
        for (int i = 0; i < FVS; ++i) acc += xo[i] * red[i * FVS + tid];
        xs[tid] = tanhf(acc);
    }
    __syncthreads();
    for (int col = tid; col < NOUT; col += 256) {
        float acc = 0.f;
        #pragma unroll
        for (int i = 0; i < FVS; ++i) acc += xs[i] * out_emb[i * NOUT + col];
        out[col] = acc;
    }
}

// ---------------- launch ----------------

typedef void (*stats_fn)(const float*, const float*, const float*, const float*,
                         const float*, const float*, const float*, const float*,
                         const float*, float*);
typedef void (*read_fn)(const float*, const float*, const float*, const float*,
                        const float*, float*);

extern "C" void kernel_launch(void* const* d_in, const int* in_sizes, int n_in,
                              void* d_out, int out_size, void* d_ws, size_t ws_size,
                              hipStream_t stream) {
    const float* x        = (const float*)d_in[0];
    const float* program  = (const float*)d_in[1];
    const float* memory0  = (const float*)d_in[2];
    const float* in_emb   = (const float*)d_in[3];
    const float* out_emb  = (const float*)d_in[4];
    const float* Wc       = (const float*)d_in[5];
    const float* bc       = (const float*)d_in[6];
    const float* Wk       = (const float*)d_in[7];
    const float* bk       = (const float*)d_in[8];
    const float* We       = (const float*)d_in[9];
    const float* be       = (const float*)d_in[10];
    const float* Wa       = (const float*)d_in[11];
    const float* ba       = (const float*)d_in[12];
    const float* Wrk      = (const float*)d_in[13];
    const float* brk      = (const float*)d_in[14];
    float* out = (float*)d_out;

    float* ws = (float*)d_ws;
    size_t off = 0;
    float* ehist   = ws + off; off += (size_t)STEPS * N_DIM;
    float* ahist   = ws + off; off += (size_t)STEPS * N_DIM;
    float* wwhist  = ws + off; off += (size_t)STEPS * M_SLOTS;
    float* kcur    = ws + off; off += N_DIM;
    float* krcur   = ws + off; off += N_DIM;
    float* ekrcur  = ws + off; off += N_DIM;
    float* eacur   = ws + off; off += N_DIM;
    float* e2cur   = ws + off; off += N_DIM;
    float* stat4   = ws + off; off += (size_t)32 * M_SLOTS;
    float* partial = ws + off; off += (size_t)NRB * N_DIM;
    float* wrcur   = ws + off; off += M_SLOTS;
    float* red     = ws + off; off += N_DIM;
    float* Xb0     = ws + off; off += FVS;
    float* Xb1     = ws + off; off += FVS;
    float* c       = ws + off; off += CDIM;

    static const stats_fn SF[STEPS] = {
        k_stats<0>, k_stats<1>, k_stats<2>, k_stats<3>,
        k_stats<4>, k_stats<5>, k_stats<6>, k_stats<7> };
    static const read_fn RF[STEPS] = {
        k_read<1>, k_read<2>, k_read<3>, k_read<4>,
        k_read<5>, k_read<6>, k_read<7>, k_read<8> };

    k_init_ctrl<<<1, 256, 0, stream>>>(x, in_emb, program, Wc, bc, Xb0, c);
    k_keys4<<<512, 256, 0, stream>>>(c, program, Wk, bk, We, be, Wa, ba, Wrk, brk,
                                     kcur, ehist, ahist, krcur, ekrcur, eacur, e2cur);

    for (int t = 0; t < STEPS; ++t) {
        // stats of mem_t (replayed from mem0) with current keys
        SF[t]<<<dim3(4, NSB), 256, 0, stream>>>(
            memory0, ehist, ahist, wwhist, kcur, krcur, ekrcur, eacur, e2cur, stat4);
        // dual softmax addressing -> ww (slot t), wr
        k_addr<<<1, 1024, 0, stream>>>(kcur, krcur, ahist + (size_t)t * N_DIM,
                                       stat4, wwhist + (size_t)t * M_SLOTS, wrcur);
        // read pass: replay updates 0..t, weight by wr
        RF[t]<<<dim3(4, NRB), 256, 0, stream>>>(
            memory0, ehist, ahist, wwhist, wrcur, partial);
        k_read_reduce<<<64, 256, 0, stream>>>(partial, red);

        const float* Xcur = (t & 1) ? Xb1 : Xb0;
        float*       Xnxt = (t & 1) ? Xb0 : Xb1;
        if (t < STEPS - 1) {
            k_exec_keys<<<512, 256, 0, stream>>>(
                Xcur, Xnxt, red, program + (t + 1) * PLEN,
                Wc, bc, Wk, bk, We, be, Wa, ba, Wrk, brk,
                kcur, ehist + (size_t)(t + 1) * N_DIM,
                ahist + (size_t)(t + 1) * N_DIM, krcur, ekrcur, eacur, e2cur);
        } else {
            k_final<<<1, 256, 0, stream>>>(Xcur, red, out_emb, out);
        }
    }
}